// Round 1
// baseline (973.229 us; speedup 1.0000x reference)
//
#include <hip/hip_runtime.h>
#include <cstdint>
#include <cstddef>

#define DM 2048
#define DFF_ 8192
#define NR 4096        // B*S rows
#define SEQ_ 2048
#define QK_SCALE 0.2973017787506803f

typedef unsigned short u16;
typedef __attribute__((ext_vector_type(8))) __bf16 bf16x8;
typedef __attribute__((ext_vector_type(8))) unsigned short us8;
typedef __attribute__((ext_vector_type(4))) unsigned short us4;
typedef __attribute__((ext_vector_type(4))) float f32x4;

static __device__ __forceinline__ u16 f2bf(float f) {
  union { float f; unsigned u; } x; x.f = f;
  unsigned r = x.u + 0x7fffu + ((x.u >> 16) & 1u);
  return (u16)(r >> 16);
}

// ---------------- fp32 -> bf16 conversion (vectorized, grid-stride) ----------
__global__ __launch_bounds__(256) void cvt_bf16_k(const float* __restrict__ in,
                                                  u16* __restrict__ out, int n4) {
  int i = blockIdx.x * 256 + threadIdx.x;
  int st = gridDim.x * 256;
  for (; i < n4; i += st) {
    float4 v = ((const float4*)in)[i];
    us4 o;
    o.x = f2bf(v.x); o.y = f2bf(v.y); o.z = f2bf(v.z); o.w = f2bf(v.w);
    ((us4*)out)[i] = o;
  }
}

// ---------------- LayerNorm: fp32 in -> bf16 out, one block per row ----------
__global__ __launch_bounds__(256) void ln_k(const float* __restrict__ X,
                                            const float* __restrict__ g,
                                            const float* __restrict__ be,
                                            u16* __restrict__ out) {
  const int row = blockIdx.x, tid = threadIdx.x;
  const float* x = X + (size_t)row * DM;
  float4 a0 = ((const float4*)x)[tid];
  float4 a1 = ((const float4*)x)[tid + 256];
  float s = a0.x + a0.y + a0.z + a0.w + a1.x + a1.y + a1.z + a1.w;
  float q = a0.x*a0.x + a0.y*a0.y + a0.z*a0.z + a0.w*a0.w
          + a1.x*a1.x + a1.y*a1.y + a1.z*a1.z + a1.w*a1.w;
  #pragma unroll
  for (int off = 32; off; off >>= 1) { s += __shfl_xor(s, off); q += __shfl_xor(q, off); }
  __shared__ float red[8];
  const int w = tid >> 6, lane = tid & 63;
  if (lane == 0) { red[w] = s; red[4 + w] = q; }
  __syncthreads();
  s = red[0] + red[1] + red[2] + red[3];
  q = red[4] + red[5] + red[6] + red[7];
  const float mean = s * (1.0f / DM);
  const float rstd = rsqrtf(q * (1.0f / DM) - mean * mean + 1e-5f);
  float4 g0 = ((const float4*)g)[tid], g1 = ((const float4*)g)[tid + 256];
  float4 b0 = ((const float4*)be)[tid], b1 = ((const float4*)be)[tid + 256];
  us4 o0, o1;
  o0.x = f2bf((a0.x - mean) * rstd * g0.x + b0.x);
  o0.y = f2bf((a0.y - mean) * rstd * g0.y + b0.y);
  o0.z = f2bf((a0.z - mean) * rstd * g0.z + b0.z);
  o0.w = f2bf((a0.w - mean) * rstd * g0.w + b0.w);
  o1.x = f2bf((a1.x - mean) * rstd * g1.x + b1.x);
  o1.y = f2bf((a1.y - mean) * rstd * g1.y + b1.y);
  o1.z = f2bf((a1.z - mean) * rstd * g1.z + b1.z);
  o1.w = f2bf((a1.w - mean) * rstd * g1.w + b1.w);
  us4* op = (us4*)(out + (size_t)row * DM);
  op[tid] = o0;
  op[tid + 256] = o1;
}

// ---------------- GEMM: C[m][n] = sum_k A[m][k] * W[n][k] (+bias, epilogue) --
// m97 structure: 128x128 tile, BK=64, 4 waves (2x2 of 64x64), global_load_lds.
// MODE 0: out bf16 = (acc+bias)*scale   MODE 1: out bf16 = gelu(acc+bias)
// MODE 2: out f32  = res + acc + bias
template<int MODE>
__global__ __launch_bounds__(256) void gemm_bt(const u16* __restrict__ A,
                                               const u16* __restrict__ W,
                                               const float* __restrict__ bias,
                                               const float* __restrict__ res,
                                               void* __restrict__ outp,
                                               int N, int K, float scale) {
  __shared__ __align__(16) u16 Alds[128 * 64];
  __shared__ __align__(16) u16 Blds[128 * 64];
  const int tid = threadIdx.x;
  const int lane = tid & 63;
  const int w = tid >> 6;
  const int hi = lane >> 4, lo = lane & 15;
  const size_t brow = (size_t)blockIdx.y * 128;
  const size_t bcol = (size_t)blockIdx.x * 128;
  const int wr = (w >> 1) * 64, wc = (w & 1) * 64;
  f32x4 acc[4][4] = {};
  for (int k0 = 0; k0 < K; k0 += 64) {
    __syncthreads();
    #pragma unroll
    for (int c = 0; c < 4; ++c) {
      const int el = (w * 4 + c) * 512 + lane * 8;
      const int row = el >> 6, col = el & 63;
      __builtin_amdgcn_global_load_lds(
          (const __attribute__((address_space(1))) void*)(A + (brow + row) * K + k0 + col),
          (__attribute__((address_space(3))) void*)(Alds + el), 16, 0, 0);
      __builtin_amdgcn_global_load_lds(
          (const __attribute__((address_space(1))) void*)(W + (bcol + row) * K + k0 + col),
          (__attribute__((address_space(3))) void*)(Blds + el), 16, 0, 0);
    }
    __syncthreads();
    #pragma unroll
    for (int ks = 0; ks < 2; ++ks) {
      bf16x8 af[4], bfr[4];
      #pragma unroll
      for (int m = 0; m < 4; ++m)
        af[m] = *(const bf16x8*)(Alds + (wr + m * 16 + lo) * 64 + ks * 32 + hi * 8);
      #pragma unroll
      for (int n = 0; n < 4; ++n)
        bfr[n] = *(const bf16x8*)(Blds + (wc + n * 16 + lo) * 64 + ks * 32 + hi * 8);
      #pragma unroll
      for (int m = 0; m < 4; ++m)
        #pragma unroll
        for (int n = 0; n < 4; ++n)
          acc[m][n] = __builtin_amdgcn_mfma_f32_16x16x32_bf16(af[m], bfr[n], acc[m][n], 0, 0, 0);
    }
  }
  #pragma unroll
  for (int n = 0; n < 4; ++n) {
    const size_t col = bcol + wc + n * 16 + lo;
    const float bv = bias[col];
    #pragma unroll
    for (int m = 0; m < 4; ++m) {
      #pragma unroll
      for (int r = 0; r < 4; ++r) {
        const size_t row = brow + wr + m * 16 + hi * 4 + r;
        const size_t idx = row * (size_t)N + col;
        float v = acc[m][n][r] + bv;
        if (MODE == 0) {
          ((u16*)outp)[idx] = f2bf(v * scale);
        } else if (MODE == 1) {
          float t = 0.7978845608028654f * (v + 0.044715f * v * v * v);
          float e2 = __expf(2.0f * t);
          float th = 1.0f - 2.0f / (e2 + 1.0f);
          ((u16*)outp)[idx] = f2bf(0.5f * v * (1.0f + th));
        } else {
          ((float*)outp)[idx] = res[idx] + v;
        }
      }
    }
  }
}

// ---------------- Flash attention (causal), bf16, per-(b,h) 64-row q-tiles ---
// 4 waves x 16 q-rows. KVBLK=32. K staged via global_load_lds with XOR-swizzled
// source (conflict-free reads); V transposed into LDS stride-72 (bank-free).
__global__ __launch_bounds__(256) void attn_k(const u16* __restrict__ Qp,
                                              const u16* __restrict__ Kp,
                                              const u16* __restrict__ Vp,
                                              u16* __restrict__ Op) {
  const int qt = blockIdx.x;          // 0..31
  const int bh = blockIdx.y;          // 0..31
  const int bb = bh >> 4, h = bh & 15;
  const int tid = threadIdx.x, lane = tid & 63, w = tid >> 6;
  const int hi = lane >> 4, lo = lane & 15;
  __shared__ __align__(16) u16 Klds[32 * 128];
  __shared__ __align__(16) u16 Vt[128 * 72];
  __shared__ __align__(16) u16 Plds[4][16 * 72];
  const size_t base = ((size_t)bb * SEQ_) * DM + (size_t)h * 128;
  const int q0 = qt * 64 + w * 16;
  bf16x8 qf[4];
  #pragma unroll
  for (int kq = 0; kq < 4; ++kq)
    qf[kq] = *(const bf16x8*)(Qp + base + (size_t)(q0 + lo) * DM + kq * 32 + hi * 8);
  f32x4 o[8] = {};
  float mrow[4], lrow[4];
  #pragma unroll
  for (int r = 0; r < 4; ++r) { mrow[r] = -1e30f; lrow[r] = 0.0f; }
  const int ntile = qt * 2 + 2;
  for (int t = 0; t < ntile; ++t) {
    const int kb = t * 32;
    __syncthreads();
    // stage K (swizzled source so LDS[row][col] = K[row][col ^ ((row&7)<<3)])
    #pragma unroll
    for (int c = 0; c < 2; ++c) {
      const int el = (w * 2 + c) * 512 + lane * 8;
      const int row = el >> 7, col = el & 127;
      const int scol = col ^ ((row & 7) << 3);
      __builtin_amdgcn_global_load_lds(
          (const __attribute__((address_space(1))) void*)(Kp + base + (size_t)(kb + row) * DM + scol),
          (__attribute__((address_space(3))) void*)(Klds + el), 16, 0, 0);
    }
    // stage V transposed: Vt[d][kv], stride 72
    {
      const int row = tid >> 3, c0 = (tid & 7) * 16;
      const u16* vs = Vp + base + (size_t)(kb + row) * DM + c0;
      us8 v0 = *(const us8*)vs;
      us8 v1 = *(const us8*)(vs + 8);
      #pragma unroll
      for (int j = 0; j < 8; ++j) {
        Vt[(c0 + j) * 72 + row] = v0[j];
        Vt[(c0 + 8 + j) * 72 + row] = v1[j];
      }
    }
    __syncthreads();
    // QK^T: 2 key sub-tiles of 16
    f32x4 sc2[2] = {};
    #pragma unroll
    for (int kt2 = 0; kt2 < 2; ++kt2) {
      const int krow = kt2 * 16 + lo;
      #pragma unroll
      for (int kq = 0; kq < 4; ++kq) {
        const int coff = (kq * 32 + hi * 8) ^ ((krow & 7) << 3);
        bf16x8 kf = *(const bf16x8*)(Klds + krow * 128 + coff);
        sc2[kt2] = __builtin_amdgcn_mfma_f32_16x16x32_bf16(qf[kq], kf, sc2[kt2], 0, 0, 0);
      }
    }
    // causal mask + online softmax
    float mt[4];
    #pragma unroll
    for (int r = 0; r < 4; ++r) mt[r] = -1e30f;
    #pragma unroll
    for (int kt2 = 0; kt2 < 2; ++kt2)
      #pragma unroll
      for (int r = 0; r < 4; ++r) {
        const int kg = kb + kt2 * 16 + lo;
        const int qg = q0 + hi * 4 + r;
        float sv = sc2[kt2][r];
        sv = (kg <= qg) ? sv : -1e30f;
        sc2[kt2][r] = sv;
        mt[r] = fmaxf(mt[r], sv);
      }
    #pragma unroll
    for (int r = 0; r < 4; ++r) {
      #pragma unroll
      for (int off = 1; off < 16; off <<= 1) mt[r] = fmaxf(mt[r], __shfl_xor(mt[r], off));
    }
    float scl[4], lt[4];
    #pragma unroll
    for (int r = 0; r < 4; ++r) {
      const float mn = fmaxf(mrow[r], mt[r]);
      scl[r] = __expf(mrow[r] - mn);
      mrow[r] = mn;
      lt[r] = 0.0f;
    }
    u16* pw = &Plds[w][0];
    #pragma unroll
    for (int kt2 = 0; kt2 < 2; ++kt2)
      #pragma unroll
      for (int r = 0; r < 4; ++r) {
        const float p = __expf(sc2[kt2][r] - mrow[r]);
        lt[r] += p;
        pw[(hi * 4 + r) * 72 + kt2 * 16 + lo] = f2bf(p);
      }
    #pragma unroll
    for (int r = 0; r < 4; ++r) {
      #pragma unroll
      for (int off = 1; off < 16; off <<= 1) lt[r] += __shfl_xor(lt[r], off);
      lrow[r] = lrow[r] * scl[r] + lt[r];
    }
    #pragma unroll
    for (int nt = 0; nt < 8; ++nt)
      #pragma unroll
      for (int r = 0; r < 4; ++r) o[nt][r] *= scl[r];
    // PV
    bf16x8 pf = *(const bf16x8*)(pw + lo * 72 + hi * 8);
    #pragma unroll
    for (int nt = 0; nt < 8; ++nt) {
      bf16x8 vf = *(const bf16x8*)(Vt + (nt * 16 + lo) * 72 + hi * 8);
      o[nt] = __builtin_amdgcn_mfma_f32_16x16x32_bf16(pf, vf, o[nt], 0, 0, 0);
    }
  }
  // epilogue
  #pragma unroll
  for (int nt = 0; nt < 8; ++nt)
    #pragma unroll
    for (int r = 0; r < 4; ++r) {
      const size_t row = q0 + hi * 4 + r;
      Op[base + row * DM + nt * 16 + lo] = f2bf(o[nt][r] / lrow[r]);
    }
}

// ---------------- launch ----------------------------------------------------
extern "C" void kernel_launch(void* const* d_in, const int* in_sizes, int n_in,
                              void* d_out, int out_size, void* d_ws, size_t ws_size,
                              hipStream_t stream) {
  (void)in_sizes; (void)n_in; (void)out_size; (void)ws_size;
  const float* X    = (const float*)d_in[0];
  const float* Wq   = (const float*)d_in[1];
  const float* bq   = (const float*)d_in[2];
  const float* Wk   = (const float*)d_in[3];
  const float* bk   = (const float*)d_in[4];
  const float* Wv   = (const float*)d_in[5];
  const float* bv   = (const float*)d_in[6];
  const float* Wo   = (const float*)d_in[7];
  const float* bo   = (const float*)d_in[8];
  const float* Win  = (const float*)d_in[9];
  const float* bin  = (const float*)d_in[10];
  const float* Wout = (const float*)d_in[11];
  const float* bout = (const float*)d_in[12];
  const float* ln1w = (const float*)d_in[13];
  const float* ln1b = (const float*)d_in[14];
  const float* ln2w = (const float*)d_in[15];
  const float* ln2b = (const float*)d_in[16];
  float* out = (float*)d_out;

  char* ws = (char*)d_ws;
  u16* wbuf = (u16*)ws;                       // 33,554,432 B (reused weight buf)
  u16* lnb  = (u16*)(ws + 33554432);          // 16,777,216 B
  u16* Qb   = (u16*)(ws + 50331648);          // 16,777,216 B
  u16* Kb   = (u16*)(ws + 67108864);          // 16,777,216 B
  u16* Vb   = (u16*)(ws + 83886080);          // 16,777,216 B
  u16* Ob   = (u16*)(ws + 100663296);         // 16,777,216 B  (end: 117,440,512)
  u16* H1   = Qb;                             // aliases Q/K/V/O (dead by then)

  // LN1
  ln_k<<<NR, 256, 0, stream>>>(X, ln1w, ln1b, lnb);
  // Q = (ln1 @ Wq^T + bq) * QK_SCALE
  cvt_bf16_k<<<2048, 256, 0, stream>>>(Wq, wbuf, DM * DM / 4);
  gemm_bt<0><<<dim3(DM / 128, NR / 128), 256, 0, stream>>>(lnb, wbuf, bq, nullptr, Qb, DM, DM, QK_SCALE);
  // K
  cvt_bf16_k<<<2048, 256, 0, stream>>>(Wk, wbuf, DM * DM / 4);
  gemm_bt<0><<<dim3(DM / 128, NR / 128), 256, 0, stream>>>(lnb, wbuf, bk, nullptr, Kb, DM, DM, QK_SCALE);
  // V
  cvt_bf16_k<<<2048, 256, 0, stream>>>(Wv, wbuf, DM * DM / 4);
  gemm_bt<0><<<dim3(DM / 128, NR / 128), 256, 0, stream>>>(lnb, wbuf, bv, nullptr, Vb, DM, DM, 1.0f);
  // attention
  attn_k<<<dim3(SEQ_ / 64, 32), 256, 0, stream>>>(Qb, Kb, Vb, Ob);
  // X1 = X + attn_out @ Wo^T + bo   -> d_out (fp32)
  cvt_bf16_k<<<2048, 256, 0, stream>>>(Wo, wbuf, DM * DM / 4);
  gemm_bt<2><<<dim3(DM / 128, NR / 128), 256, 0, stream>>>(Ob, wbuf, bo, X, out, DM, DM, 0.0f);
  // LN2
  ln_k<<<NR, 256, 0, stream>>>(out, ln2w, ln2b, lnb);
  // H1 = gelu(ln2 @ Win^T + bin)
  cvt_bf16_k<<<2048, 256, 0, stream>>>(Win, wbuf, DFF_ * DM / 4);
  gemm_bt<1><<<dim3(DFF_ / 128, NR / 128), 256, 0, stream>>>(lnb, wbuf, bin, nullptr, H1, DFF_, DM, 0.0f);
  // out = X1 + H1 @ Wout^T + bout   (in-place residual on d_out)
  cvt_bf16_k<<<2048, 256, 0, stream>>>(Wout, wbuf, DM * DFF_ / 4);
  gemm_bt<2><<<dim3(DM / 128, NR / 128), 256, 0, stream>>>(H1, wbuf, bout, out, out, DM, DFF_, 0.0f);
}

// Round 2
// 766.724 us; speedup vs baseline: 1.2693x; 1.2693x over previous
//
#include <hip/hip_runtime.h>
#include <cstdint>
#include <cstddef>

#define DM 2048
#define DFF_ 8192
#define NR 4096        // B*S rows
#define SEQ_ 2048
#define KVB 64
#define QK_SCALE 0.2973017787506803f

typedef unsigned short u16;
typedef __attribute__((ext_vector_type(8))) __bf16 bf16x8;
typedef __attribute__((ext_vector_type(8))) unsigned short us8;
typedef __attribute__((ext_vector_type(4))) unsigned short us4;
typedef __attribute__((ext_vector_type(4))) float f32x4;

static __device__ __forceinline__ u16 f2bf(float f) {
  union { float f; unsigned u; } x; x.f = f;
  unsigned r = x.u + 0x7fffu + ((x.u >> 16) & 1u);
  return (u16)(r >> 16);
}

// ---------------- fp32 -> bf16 conversion (vectorized, grid-stride) ----------
__global__ __launch_bounds__(256) void cvt_bf16_k(const float* __restrict__ in,
                                                  u16* __restrict__ out, int n4) {
  int i = blockIdx.x * 256 + threadIdx.x;
  int st = gridDim.x * 256;
  for (; i < n4; i += st) {
    float4 v = ((const float4*)in)[i];
    us4 o;
    o.x = f2bf(v.x); o.y = f2bf(v.y); o.z = f2bf(v.z); o.w = f2bf(v.w);
    ((us4*)out)[i] = o;
  }
}

// ---------------- LayerNorm: fp32 in -> bf16 out, one block per row ----------
__global__ __launch_bounds__(256) void ln_k(const float* __restrict__ X,
                                            const float* __restrict__ g,
                                            const float* __restrict__ be,
                                            u16* __restrict__ out) {
  const int row = blockIdx.x, tid = threadIdx.x;
  const float* x = X + (size_t)row * DM;
  float4 a0 = ((const float4*)x)[tid];
  float4 a1 = ((const float4*)x)[tid + 256];
  float s = a0.x + a0.y + a0.z + a0.w + a1.x + a1.y + a1.z + a1.w;
  float q = a0.x*a0.x + a0.y*a0.y + a0.z*a0.z + a0.w*a0.w
          + a1.x*a1.x + a1.y*a1.y + a1.z*a1.z + a1.w*a1.w;
  #pragma unroll
  for (int off = 32; off; off >>= 1) { s += __shfl_xor(s, off); q += __shfl_xor(q, off); }
  __shared__ float red[8];
  const int w = tid >> 6, lane = tid & 63;
  if (lane == 0) { red[w] = s; red[4 + w] = q; }
  __syncthreads();
  s = red[0] + red[1] + red[2] + red[3];
  q = red[4] + red[5] + red[6] + red[7];
  const float mean = s * (1.0f / DM);
  const float rstd = rsqrtf(q * (1.0f / DM) - mean * mean + 1e-5f);
  float4 g0 = ((const float4*)g)[tid], g1 = ((const float4*)g)[tid + 256];
  float4 b0 = ((const float4*)be)[tid], b1 = ((const float4*)be)[tid + 256];
  us4 o0, o1;
  o0.x = f2bf((a0.x - mean) * rstd * g0.x + b0.x);
  o0.y = f2bf((a0.y - mean) * rstd * g0.y + b0.y);
  o0.z = f2bf((a0.z - mean) * rstd * g0.z + b0.z);
  o0.w = f2bf((a0.w - mean) * rstd * g0.w + b0.w);
  o1.x = f2bf((a1.x - mean) * rstd * g1.x + b1.x);
  o1.y = f2bf((a1.y - mean) * rstd * g1.y + b1.y);
  o1.z = f2bf((a1.z - mean) * rstd * g1.z + b1.z);
  o1.w = f2bf((a1.w - mean) * rstd * g1.w + b1.w);
  us4* op = (us4*)(out + (size_t)row * DM);
  op[tid] = o0;
  op[tid + 256] = o1;
}

// ---------------- GEMM: C[m][n] = sum_k A[m][k] * W[n][k] (+bias, epilogue) --
// m97 structure: 128x128 tile, BK=64, 4 waves (2x2 of 64x64), global_load_lds.
// MODE 0: out bf16 = (acc+bias)*scale   MODE 1: out bf16 = gelu(acc+bias)
// MODE 2: out f32  = res + acc + bias   MODE 3: out bf16 transposed [col][row]
template<int MODE>
__global__ __launch_bounds__(256) void gemm_bt(const u16* __restrict__ A,
                                               const u16* __restrict__ W,
                                               const float* __restrict__ bias,
                                               const float* __restrict__ res,
                                               void* __restrict__ outp,
                                               int N, int K, float scale) {
  __shared__ __align__(16) u16 Alds[128 * 64];
  __shared__ __align__(16) u16 Blds[128 * 64];
  const int tid = threadIdx.x;
  const int lane = tid & 63;
  const int w = tid >> 6;
  const int hi = lane >> 4, lo = lane & 15;
  const size_t brow = (size_t)blockIdx.y * 128;
  const size_t bcol = (size_t)blockIdx.x * 128;
  const int wr = (w >> 1) * 64, wc = (w & 1) * 64;
  f32x4 acc[4][4] = {};
  for (int k0 = 0; k0 < K; k0 += 64) {
    __syncthreads();
    #pragma unroll
    for (int c = 0; c < 4; ++c) {
      const int el = (w * 4 + c) * 512 + lane * 8;
      const int row = el >> 6, col = el & 63;
      __builtin_amdgcn_global_load_lds(
          (const __attribute__((address_space(1))) void*)(A + (brow + row) * K + k0 + col),
          (__attribute__((address_space(3))) void*)(Alds + el), 16, 0, 0);
      __builtin_amdgcn_global_load_lds(
          (const __attribute__((address_space(1))) void*)(W + (bcol + row) * K + k0 + col),
          (__attribute__((address_space(3))) void*)(Blds + el), 16, 0, 0);
    }
    __syncthreads();
    #pragma unroll
    for (int ks = 0; ks < 2; ++ks) {
      bf16x8 af[4], bfr[4];
      #pragma unroll
      for (int m = 0; m < 4; ++m)
        af[m] = *(const bf16x8*)(Alds + (wr + m * 16 + lo) * 64 + ks * 32 + hi * 8);
      #pragma unroll
      for (int n = 0; n < 4; ++n)
        bfr[n] = *(const bf16x8*)(Blds + (wc + n * 16 + lo) * 64 + ks * 32 + hi * 8);
      #pragma unroll
      for (int m = 0; m < 4; ++m)
        #pragma unroll
        for (int n = 0; n < 4; ++n)
          acc[m][n] = __builtin_amdgcn_mfma_f32_16x16x32_bf16(af[m], bfr[n], acc[m][n], 0, 0, 0);
    }
  }
  if (MODE == 3) {
    // transposed bf16 store: out[col][row], rows packed 4-wide (us4)
    #pragma unroll
    for (int n = 0; n < 4; ++n) {
      const size_t col = bcol + wc + n * 16 + lo;
      const float bv = bias[col];
      #pragma unroll
      for (int m = 0; m < 4; ++m) {
        const size_t rowb = brow + wr + m * 16 + hi * 4;
        us4 ov;
        #pragma unroll
        for (int r = 0; r < 4; ++r) ov[r] = f2bf(acc[m][n][r] + bv);
        *(us4*)((u16*)outp + col * (size_t)NR + rowb) = ov;
      }
    }
    return;
  }
  #pragma unroll
  for (int n = 0; n < 4; ++n) {
    const size_t col = bcol + wc + n * 16 + lo;
    const float bv = bias[col];
    #pragma unroll
    for (int m = 0; m < 4; ++m) {
      #pragma unroll
      for (int r = 0; r < 4; ++r) {
        const size_t row = brow + wr + m * 16 + hi * 4 + r;
        const size_t idx = row * (size_t)N + col;
        float v = acc[m][n][r] + bv;
        if (MODE == 0) {
          ((u16*)outp)[idx] = f2bf(v * scale);
        } else if (MODE == 1) {
          float t = 0.7978845608028654f * (v + 0.044715f * v * v * v);
          float e2 = __expf(2.0f * t);
          float th = 1.0f - 2.0f / (e2 + 1.0f);
          ((u16*)outp)[idx] = f2bf(0.5f * v * (1.0f + th));
        } else {
          ((float*)outp)[idx] = res[idx] + v;
        }
      }
    }
  }
}

// ---------------- Flash attention (causal), bf16 ----------------------------
// 4 waves x 16 q-rows (QBLK=64), KVBLK=64. K and V^T staged via global_load_lds
// with pre-swizzled global source (XOR chunk swizzle, conflict-free reads).
// V is consumed pre-transposed (produced by the V-projection GEMM, MODE 3).
// P goes through per-wave LDS as packed bf16 pairs (u32), XOR-swizzled.
// Grid: 1024 blocks, heaviest q-tiles first (causal load balance).
__global__ __launch_bounds__(256) void attn_k(const u16* __restrict__ Qp,
                                              const u16* __restrict__ Kp,
                                              const u16* __restrict__ Vtp,
                                              u16* __restrict__ Op) {
  const int wid = blockIdx.x;               // 0..1023
  const int qt = 31 - (wid >> 5);           // descending work
  const int bh = wid & 31;
  const int bb = bh >> 4, h = bh & 15;
  const int tid = threadIdx.x, lane = tid & 63, w = tid >> 6;
  const int hi = lane >> 4, lo = lane & 15;
  __shared__ __align__(16) u16 Klds[KVB * 128];       // [kv][d]  swizzled
  __shared__ __align__(16) u16 Vlds[128 * KVB];       // [d][kv]  swizzled
  __shared__ __align__(16) unsigned P32[4][16 * 32];  // per-wave [qrow][kpair] swizzled
  const size_t baseQ = ((size_t)bb * SEQ_) * DM + (size_t)h * 128;
  const size_t baseV = (size_t)h * 128 * NR + (size_t)bb * SEQ_;
  const int q0 = qt * 64 + w * 16;
  bf16x8 qf[4];
  #pragma unroll
  for (int kq = 0; kq < 4; ++kq)
    qf[kq] = *(const bf16x8*)(Qp + baseQ + (size_t)(q0 + lo) * DM + kq * 32 + hi * 8);
  f32x4 o[8] = {};
  float mrow[4], lrow[4];
  #pragma unroll
  for (int r = 0; r < 4; ++r) { mrow[r] = -1e30f; lrow[r] = 0.0f; }
  unsigned* pw = &P32[w][0];
  const int ntile = qt + 1;
  for (int t = 0; t < ntile; ++t) {
    const int kb = t * KVB;
    __syncthreads();
    // stage K tile: 64 rows x 128 cols (bf16), source pre-swizzled
    #pragma unroll
    for (int c = 0; c < 4; ++c) {
      const int el = ((w * 4 + c) * 64 + lane) * 8;
      const int row = el >> 7, col = el & 127;
      const int scol = col ^ ((row & 7) << 3);
      __builtin_amdgcn_global_load_lds(
          (const __attribute__((address_space(1))) void*)(Kp + baseQ + (size_t)(kb + row) * DM + scol),
          (__attribute__((address_space(3))) void*)(Klds + el), 16, 0, 0);
    }
    // stage V^T tile: 128 rows (d) x 64 cols (s), source pre-swizzled
    #pragma unroll
    for (int c = 0; c < 4; ++c) {
      const int el = ((w * 4 + c) * 64 + lane) * 8;
      const int row = el >> 6, col = el & 63;
      const int scol = col ^ ((row & 7) << 3);
      __builtin_amdgcn_global_load_lds(
          (const __attribute__((address_space(1))) void*)(Vtp + baseV + (size_t)row * NR + kb + scol),
          (__attribute__((address_space(3))) void*)(Vlds + el), 16, 0, 0);
    }
    __syncthreads();
    // QK^T: 4 key sub-tiles of 16
    f32x4 sc[4] = {};
    #pragma unroll
    for (int kt = 0; kt < 4; ++kt) {
      const int krow = kt * 16 + lo;
      #pragma unroll
      for (int kq = 0; kq < 4; ++kq) {
        const int coff = (kq * 32 + hi * 8) ^ ((krow & 7) << 3);
        bf16x8 kf = *(const bf16x8*)(Klds + krow * 128 + coff);
        sc[kt] = __builtin_amdgcn_mfma_f32_16x16x32_bf16(qf[kq], kf, sc[kt], 0, 0, 0);
      }
    }
    // causal mask + per-row max
    float mt[4];
    #pragma unroll
    for (int r = 0; r < 4; ++r) mt[r] = -1e30f;
    #pragma unroll
    for (int kt = 0; kt < 4; ++kt) {
      const int kg = kb + kt * 16 + lo;
      #pragma unroll
      for (int r = 0; r < 4; ++r) {
        const int qg = q0 + hi * 4 + r;
        float sv = sc[kt][r];
        sv = (kg <= qg) ? sv : -1e30f;
        sc[kt][r] = sv;
        mt[r] = fmaxf(mt[r], sv);
      }
    }
    #pragma unroll
    for (int r = 0; r < 4; ++r) {
      #pragma unroll
      for (int off = 1; off < 16; off <<= 1) mt[r] = fmaxf(mt[r], __shfl_xor(mt[r], off));
    }
    float scl[4], lt[4];
    #pragma unroll
    for (int r = 0; r < 4; ++r) {
      const float mn = fmaxf(mrow[r], mt[r]);
      scl[r] = __expf(mrow[r] - mn);
      mrow[r] = mn;
      lt[r] = 0.0f;
    }
    float pv_[4][4];
    #pragma unroll
    for (int kt = 0; kt < 4; ++kt)
      #pragma unroll
      for (int r = 0; r < 4; ++r) {
        const float p = __expf(sc[kt][r] - mrow[r]);
        pv_[kt][r] = p;
        lt[r] += p;
      }
    #pragma unroll
    for (int r = 0; r < 4; ++r) {
      #pragma unroll
      for (int off = 1; off < 16; off <<= 1) lt[r] += __shfl_xor(lt[r], off);
      lrow[r] = lrow[r] * scl[r] + lt[r];
    }
    #pragma unroll
    for (int nt = 0; nt < 8; ++nt)
      #pragma unroll
      for (int r = 0; r < 4; ++r) o[nt][r] *= scl[r];
    // pack P -> per-wave LDS: u32 = (bf16 even-k | bf16 odd-k), chunk-XOR swizzle
    #pragma unroll
    for (int kt = 0; kt < 4; ++kt)
      #pragma unroll
      for (int r = 0; r < 4; ++r) {
        const float own = pv_[kt][r];
        const float pp = __shfl_xor(own, 1);
        const unsigned lo16 = (lane & 1) ? f2bf(pp) : f2bf(own);
        const unsigned hi16 = (lane & 1) ? f2bf(own) : f2bf(pp);
        const unsigned pk = lo16 | (hi16 << 16);
        if ((lane & 1) == (kt >> 1)) {
          const int row = hi * 4 + r;
          const int kp = kt * 8 + (lo >> 1);
          const int kps = (((kp >> 2) ^ (row & 7)) << 2) | (kp & 3);
          pw[row * 32 + kps] = pk;
        }
      }
    // PV: O[16q][128d] += P[16q][64k] * V^T[128d][64k]
    #pragma unroll
    for (int half = 0; half < 2; ++half) {
      const int ch = (half * 4 + hi) ^ (lo & 7);
      bf16x8 pf = *(const bf16x8*)((const u16*)(pw + lo * 32 + ch * 4));
      #pragma unroll
      for (int nt = 0; nt < 8; ++nt) {
        const int vrow = nt * 16 + lo;
        const int coff = (half * 32 + hi * 8) ^ ((vrow & 7) << 3);
        bf16x8 vf = *(const bf16x8*)(Vlds + vrow * 64 + coff);
        o[nt] = __builtin_amdgcn_mfma_f32_16x16x32_bf16(pf, vf, o[nt], 0, 0, 0);
      }
    }
  }
  // epilogue
  float inv[4];
  #pragma unroll
  for (int r = 0; r < 4; ++r) inv[r] = 1.0f / lrow[r];
  #pragma unroll
  for (int nt = 0; nt < 8; ++nt)
    #pragma unroll
    for (int r = 0; r < 4; ++r) {
      const size_t row = q0 + hi * 4 + r;
      Op[baseQ + row * DM + nt * 16 + lo] = f2bf(o[nt][r] * inv[r]);
    }
}

// ---------------- launch ----------------------------------------------------
extern "C" void kernel_launch(void* const* d_in, const int* in_sizes, int n_in,
                              void* d_out, int out_size, void* d_ws, size_t ws_size,
                              hipStream_t stream) {
  (void)in_sizes; (void)n_in; (void)out_size; (void)ws_size;
  const float* X    = (const float*)d_in[0];
  const float* Wq   = (const float*)d_in[1];
  const float* bq   = (const float*)d_in[2];
  const float* Wk   = (const float*)d_in[3];
  const float* bk   = (const float*)d_in[4];
  const float* Wv   = (const float*)d_in[5];
  const float* bv   = (const float*)d_in[6];
  const float* Wo   = (const float*)d_in[7];
  const float* bo   = (const float*)d_in[8];
  const float* Win  = (const float*)d_in[9];
  const float* bin  = (const float*)d_in[10];
  const float* Wout = (const float*)d_in[11];
  const float* bout = (const float*)d_in[12];
  const float* ln1w = (const float*)d_in[13];
  const float* ln1b = (const float*)d_in[14];
  const float* ln2w = (const float*)d_in[15];
  const float* ln2b = (const float*)d_in[16];
  float* out = (float*)d_out;

  char* ws = (char*)d_ws;
  u16* wbuf = (u16*)ws;                       // 33,554,432 B (reused weight buf)
  u16* lnb  = (u16*)(ws + 33554432);          // 16,777,216 B
  u16* Qb   = (u16*)(ws + 50331648);          // 16,777,216 B
  u16* Kb   = (u16*)(ws + 67108864);          // 16,777,216 B
  u16* Vtb  = (u16*)(ws + 83886080);          // 16,777,216 B  (V transposed [d_model][b*s])
  u16* Ob   = (u16*)(ws + 100663296);         // 16,777,216 B  (end: 117,440,512)
  u16* H1   = Qb;                             // aliases Q/K/V/O (dead by then)

  // LN1
  ln_k<<<NR, 256, 0, stream>>>(X, ln1w, ln1b, lnb);
  // Q = (ln1 @ Wq^T + bq) * QK_SCALE
  cvt_bf16_k<<<2048, 256, 0, stream>>>(Wq, wbuf, DM * DM / 4);
  gemm_bt<0><<<dim3(DM / 128, NR / 128), 256, 0, stream>>>(lnb, wbuf, bq, nullptr, Qb, DM, DM, QK_SCALE);
  // K
  cvt_bf16_k<<<2048, 256, 0, stream>>>(Wk, wbuf, DM * DM / 4);
  gemm_bt<0><<<dim3(DM / 128, NR / 128), 256, 0, stream>>>(lnb, wbuf, bk, nullptr, Kb, DM, DM, QK_SCALE);
  // V (written transposed: Vt[h*128+d][b*2048+s])
  cvt_bf16_k<<<2048, 256, 0, stream>>>(Wv, wbuf, DM * DM / 4);
  gemm_bt<3><<<dim3(DM / 128, NR / 128), 256, 0, stream>>>(lnb, wbuf, bv, nullptr, Vtb, DM, DM, 1.0f);
  // attention
  attn_k<<<1024, 256, 0, stream>>>(Qb, Kb, Vtb, Ob);
  // X1 = X + attn_out @ Wo^T + bo   -> d_out (fp32)
  cvt_bf16_k<<<2048, 256, 0, stream>>>(Wo, wbuf, DM * DM / 4);
  gemm_bt<2><<<dim3(DM / 128, NR / 128), 256, 0, stream>>>(Ob, wbuf, bo, X, out, DM, DM, 0.0f);
  // LN2
  ln_k<<<NR, 256, 0, stream>>>(out, ln2w, ln2b, lnb);
  // H1 = gelu(ln2 @ Win^T + bin)
  cvt_bf16_k<<<2048, 256, 0, stream>>>(Win, wbuf, DFF_ * DM / 4);
  gemm_bt<1><<<dim3(DFF_ / 128, NR / 128), 256, 0, stream>>>(lnb, wbuf, bin, nullptr, H1, DFF_, DM, 0.0f);
  // out = X1 + H1 @ Wout^T + bout   (in-place residual on d_out)
  cvt_bf16_k<<<2048, 256, 0, stream>>>(Wout, wbuf, DM * DFF_ / 4);
  gemm_bt<2><<<dim3(DM / 128, NR / 128), 256, 0, stream>>>(H1, wbuf, bout, out, out, DM, DFF_, 0.0f);
}

// Round 3
// 657.954 us; speedup vs baseline: 1.4792x; 1.1653x over previous
//
#include <hip/hip_runtime.h>
#include <cstdint>
#include <cstddef>

#define DM 2048
#define DFF_ 8192
#define NR 4096        // B*S rows
#define SEQ_ 2048
#define KVB 64
#define QK_SCALE 0.2973017787506803f

typedef unsigned short u16;
typedef __attribute__((ext_vector_type(8))) __bf16 bf16x8;
typedef __attribute__((ext_vector_type(8))) unsigned short us8;
typedef __attribute__((ext_vector_type(4))) unsigned short us4;
typedef __attribute__((ext_vector_type(4))) float f32x4;

static __device__ __forceinline__ u16 f2bf(float f) {
  union { float f; unsigned u; } x; x.f = f;
  unsigned r = x.u + 0x7fffu + ((x.u >> 16) & 1u);
  return (u16)(r >> 16);
}

#define GLL(srcp, dstp) __builtin_amdgcn_global_load_lds( \
    (const __attribute__((address_space(1))) void*)(srcp), \
    (__attribute__((address_space(3))) void*)(dstp), 16, 0, 0)
#define BAR() __builtin_amdgcn_s_barrier()
#define LGKM0() do { asm volatile("s_waitcnt lgkmcnt(0)" ::: "memory"); \
                     __builtin_amdgcn_sched_barrier(0); } while (0)

// ---------------- fp32 -> bf16 conversion (vectorized, grid-stride) ----------
__global__ __launch_bounds__(256) void cvt_bf16_k(const float* __restrict__ in,
                                                  u16* __restrict__ out, int n4) {
  int i = blockIdx.x * 256 + threadIdx.x;
  int st = gridDim.x * 256;
  for (; i < n4; i += st) {
    float4 v = ((const float4*)in)[i];
    us4 o;
    o.x = f2bf(v.x); o.y = f2bf(v.y); o.z = f2bf(v.z); o.w = f2bf(v.w);
    ((us4*)out)[i] = o;
  }
}

__global__ __launch_bounds__(256) void concat3_k(const float* a, const float* b,
                                                 const float* c, float* o) {
  int i = blockIdx.x * 256 + threadIdx.x;
  if (i < DM) { o[i] = a[i]; o[DM + i] = b[i]; o[2 * DM + i] = c[i]; }
}

// ---------------- LayerNorm: fp32 in -> bf16 out, one block per row ----------
__global__ __launch_bounds__(256) void ln_k(const float* __restrict__ X,
                                            const float* __restrict__ g,
                                            const float* __restrict__ be,
                                            u16* __restrict__ out) {
  const int row = blockIdx.x, tid = threadIdx.x;
  const float* x = X + (size_t)row * DM;
  float4 a0 = ((const float4*)x)[tid];
  float4 a1 = ((const float4*)x)[tid + 256];
  float s = a0.x + a0.y + a0.z + a0.w + a1.x + a1.y + a1.z + a1.w;
  float q = a0.x*a0.x + a0.y*a0.y + a0.z*a0.z + a0.w*a0.w
          + a1.x*a1.x + a1.y*a1.y + a1.z*a1.z + a1.w*a1.w;
  #pragma unroll
  for (int off = 32; off; off >>= 1) { s += __shfl_xor(s, off); q += __shfl_xor(q, off); }
  __shared__ float red[8];
  const int w = tid >> 6, lane = tid & 63;
  if (lane == 0) { red[w] = s; red[4 + w] = q; }
  __syncthreads();
  s = red[0] + red[1] + red[2] + red[3];
  q = red[4] + red[5] + red[6] + red[7];
  const float mean = s * (1.0f / DM);
  const float rstd = rsqrtf(q * (1.0f / DM) - mean * mean + 1e-5f);
  float4 g0 = ((const float4*)g)[tid], g1 = ((const float4*)g)[tid + 256];
  float4 b0 = ((const float4*)be)[tid], b1 = ((const float4*)be)[tid + 256];
  us4 o0, o1;
  o0.x = f2bf((a0.x - mean) * rstd * g0.x + b0.x);
  o0.y = f2bf((a0.y - mean) * rstd * g0.y + b0.y);
  o0.z = f2bf((a0.z - mean) * rstd * g0.z + b0.z);
  o0.w = f2bf((a0.w - mean) * rstd * g0.w + b0.w);
  o1.x = f2bf((a1.x - mean) * rstd * g1.x + b1.x);
  o1.y = f2bf((a1.y - mean) * rstd * g1.y + b1.y);
  o1.z = f2bf((a1.z - mean) * rstd * g1.z + b1.z);
  o1.w = f2bf((a1.w - mean) * rstd * g1.w + b1.w);
  us4* op = (us4*)(out + (size_t)row * DM);
  op[tid] = o0;
  op[tid + 256] = o1;
}

// ---------------- 8-phase 256-tile GEMM (T2+T3+T4+T5), BM=256, BK=64 --------
// 512 threads = 8 waves (2 M x 4 N). Per-wave output 128 x (BN/4).
// K-tile = 4 phases, each: {ds_read frags | stage | bar | lgkm0 | MFMA | bar}.
// Counted vmcnt once per K-tile (6 for BN=256, 4 for BN=128) - never 0.
// LDS XOR swizzle (16B granular) both-sides via pre-swizzled global source.
// MODE 1: bf16 gelu(acc+b) -> o0[row*N+col]
// MODE 2: f32  res + acc + b -> o0
// MODE 4: QKV fused: col<2048 -> Q=o0 (bf16,*QK_SCALE), <4096 -> K=o1 (scaled),
//         else V^T -> o2[c2*NR+row] (bf16, us4-packed rows)
template<int MODE, int BN>
__global__ __launch_bounds__(512, 2) void gemm8p(
    const u16* __restrict__ A, const u16* __restrict__ W,
    const float* __restrict__ bias, const float* __restrict__ res,
    void* __restrict__ o0, void* __restrict__ o1, void* __restrict__ o2,
    int N, int K, int NX) {
  constexpr int NREP = BN / 64;    // 4 or 2 col-fragments per wave
  constexpr int NH = NREP / 2;     // per phase-half
  constexpr int LB = BN / 128;     // global_load_lds per B half-stage
  constexpr int ASZ = 256 * 64;
  constexpr int BSZ = BN * 64;
  extern __shared__ __align__(16) u16 lds[];
  const int tid = threadIdx.x, lane = tid & 63, w = tid >> 6;
  const int hi = lane >> 4, lo = lane & 15;
  // bijective XCD swizzle (grid % 8 == 0 for all our launches)
  const int bid = blockIdx.x;
  const int swz = (bid & 7) * ((int)gridDim.x >> 3) + (bid >> 3);
  const size_t brow = (size_t)(swz / NX) * 256;
  const size_t bcol = (size_t)(swz % NX) * BN;
  const int wr = (w >> 2) * 128, wc = (w & 3) * (BN / 4);
  // staging addressing (per-lane linear LDS dst, pre-swizzled global src)
  const int rA = tid >> 3;               // 0..63
  const int cA = (tid & 7) * 8;
  const int scol = cA ^ ((rA & 7) << 3);
  const int NT = K >> 6;

#define STAGE_A(h, tt) do { \
    u16* ab_ = lds + ((tt) & 1) * (ASZ + BSZ); \
    const size_t k0_ = (size_t)(tt) * 64; \
    _Pragma("unroll") \
    for (int c_ = 0; c_ < 2; ++c_) { \
      const int row_ = (h) * 128 + c_ * 64 + rA; \
      GLL(A + (brow + row_) * (size_t)K + k0_ + scol, ab_ + row_ * 64 + cA); \
    } } while (0)
#define STAGE_B(h, tt) do { \
    u16* bb_ = lds + ((tt) & 1) * (ASZ + BSZ) + ASZ; \
    const size_t k0_ = (size_t)(tt) * 64; \
    _Pragma("unroll") \
    for (int c_ = 0; c_ < LB; ++c_) { \
      const int row_ = (h) * (BN / 2) + c_ * 64 + rA; \
      GLL(W + (bcol + row_) * (size_t)K + k0_ + scol, bb_ + row_ * 64 + cA); \
    } } while (0)
#define VMC_STEADY() do { if constexpr (BN == 256) \
      asm volatile("s_waitcnt vmcnt(6)" ::: "memory"); \
    else asm volatile("s_waitcnt vmcnt(4)" ::: "memory"); \
    __builtin_amdgcn_sched_barrier(0); } while (0)

  const int koff[2] = { (hi * 8) ^ ((lo & 7) << 3), (32 + hi * 8) ^ ((lo & 7) << 3) };
  f32x4 acc[8][NREP] = {};
  bf16x8 af[4][2], b0f[NH][2], b1f[NH][2];

  // prologue: tile0 fully + tile1 {B0,B1,A0}; A1(t1) goes at t0's P1
  STAGE_B(0, 0); STAGE_B(1, 0); STAGE_A(0, 0); STAGE_A(1, 0);
  STAGE_B(0, 1); STAGE_B(1, 1); STAGE_A(0, 1);
  VMC_STEADY();            // tile0 landed; tile1's 3 units in flight
  BAR();

  for (int t = 0; t < NT; ++t) {
    const u16* Ab = lds + (t & 1) * (ASZ + BSZ);
    const u16* Bb = Ab + ASZ;
    // ---- P1: quad(mh0,nh0); stage A1(t+1) -> other buffer
    #pragma unroll
    for (int m = 0; m < 4; ++m)
      #pragma unroll
      for (int ks = 0; ks < 2; ++ks)
        af[m][ks] = *(const bf16x8*)(Ab + (wr + m * 16 + lo) * 64 + koff[ks]);
    #pragma unroll
    for (int n = 0; n < NH; ++n)
      #pragma unroll
      for (int ks = 0; ks < 2; ++ks)
        b0f[n][ks] = *(const bf16x8*)(Bb + (wc + n * 16 + lo) * 64 + koff[ks]);
    if (t + 1 < NT) STAGE_A(1, t + 1);
    BAR(); LGKM0();
    __builtin_amdgcn_s_setprio(1);
    #pragma unroll
    for (int m = 0; m < 4; ++m)
      #pragma unroll
      for (int n = 0; n < NH; ++n)
        #pragma unroll
        for (int ks = 0; ks < 2; ++ks)
          acc[m][n] = __builtin_amdgcn_mfma_f32_16x16x32_bf16(af[m][ks], b0f[n][ks], acc[m][n], 0, 0, 0);
    __builtin_amdgcn_s_setprio(0);
    BAR();
    // ---- P2: quad(mh0,nh1)
    #pragma unroll
    for (int n = 0; n < NH; ++n)
      #pragma unroll
      for (int ks = 0; ks < 2; ++ks)
        b1f[n][ks] = *(const bf16x8*)(Bb + (wc + (NH + n) * 16 + lo) * 64 + koff[ks]);
    BAR(); LGKM0();
    __builtin_amdgcn_s_setprio(1);
    #pragma unroll
    for (int m = 0; m < 4; ++m)
      #pragma unroll
      for (int n = 0; n < NH; ++n)
        #pragma unroll
        for (int ks = 0; ks < 2; ++ks)
          acc[m][NH + n] = __builtin_amdgcn_mfma_f32_16x16x32_bf16(af[m][ks], b1f[n][ks], acc[m][NH + n], 0, 0, 0);
    __builtin_amdgcn_s_setprio(0);
    BAR();
    // ---- P3: quad(mh1,nh0); stage B0(t+2) (B reads done at P2)
    #pragma unroll
    for (int m = 0; m < 4; ++m)
      #pragma unroll
      for (int ks = 0; ks < 2; ++ks)
        af[m][ks] = *(const bf16x8*)(Ab + (wr + (4 + m) * 16 + lo) * 64 + koff[ks]);
    if (t + 2 < NT) STAGE_B(0, t + 2);
    BAR(); LGKM0();
    __builtin_amdgcn_s_setprio(1);
    #pragma unroll
    for (int m = 0; m < 4; ++m)
      #pragma unroll
      for (int n = 0; n < NH; ++n)
        #pragma unroll
        for (int ks = 0; ks < 2; ++ks)
          acc[4 + m][n] = __builtin_amdgcn_mfma_f32_16x16x32_bf16(af[m][ks], b0f[n][ks], acc[4 + m][n], 0, 0, 0);
    __builtin_amdgcn_s_setprio(0);
    BAR();
    // ---- P4: quad(mh1,nh1); stage B1,A0(t+2) (A reads done at P3); counted vmcnt
    if (t + 2 < NT) { STAGE_B(1, t + 2); STAGE_A(0, t + 2); }
    BAR();
    __builtin_amdgcn_s_setprio(1);
    #pragma unroll
    for (int m = 0; m < 4; ++m)
      #pragma unroll
      for (int n = 0; n < NH; ++n)
        #pragma unroll
        for (int ks = 0; ks < 2; ++ks)
          acc[4 + m][NH + n] = __builtin_amdgcn_mfma_f32_16x16x32_bf16(af[m][ks], b1f[n][ks], acc[4 + m][NH + n], 0, 0, 0);
    __builtin_amdgcn_s_setprio(0);
    if (t + 2 < NT) { VMC_STEADY(); }
    else if (t + 1 < NT) { asm volatile("s_waitcnt vmcnt(0)" ::: "memory"); }
    BAR();
  }
#undef STAGE_A
#undef STAGE_B
#undef VMC_STEADY
  // ---- epilogue
  #pragma unroll
  for (int m = 0; m < 8; ++m) {
    #pragma unroll
    for (int n = 0; n < NREP; ++n) {
      const size_t col = bcol + wc + n * 16 + lo;
      const float bv = bias[col];
      const size_t rowb = brow + wr + m * 16 + hi * 4;
      if (MODE == 4) {
        const int which = (int)(col >> 11);
        const size_t c2 = col & 2047;
        if (which == 2) {
          us4 ov;
          #pragma unroll
          for (int r = 0; r < 4; ++r) ov[r] = f2bf(acc[m][n][r] + bv);
          *(us4*)((u16*)o2 + c2 * (size_t)NR + rowb) = ov;
        } else {
          u16* dst = (u16*)(which ? o1 : o0);
          #pragma unroll
          for (int r = 0; r < 4; ++r)
            dst[(rowb + r) * (size_t)DM + c2] = f2bf((acc[m][n][r] + bv) * QK_SCALE);
        }
      } else if (MODE == 1) {
        u16* dst = (u16*)o0;
        #pragma unroll
        for (int r = 0; r < 4; ++r) {
          float v = acc[m][n][r] + bv;
          float tt = 0.7978845608028654f * (v + 0.044715f * v * v * v);
          float e2 = __expf(2.0f * tt);
          float th = 1.0f - 2.0f / (e2 + 1.0f);
          dst[(rowb + r) * (size_t)N + col] = f2bf(0.5f * v * (1.0f + th));
        }
      } else {
        float* po = (float*)o0;
        #pragma unroll
        for (int r = 0; r < 4; ++r) {
          const size_t idx = (rowb + r) * (size_t)N + col;
          po[idx] = res[idx] + acc[m][n][r] + bv;
        }
      }
    }
  }
}

// ---------------- Flash attention (causal), bf16 ----------------------------
__global__ __launch_bounds__(256) void attn_k(const u16* __restrict__ Qp,
                                              const u16* __restrict__ Kp,
                                              const u16* __restrict__ Vtp,
                                              u16* __restrict__ Op) {
  const int wid = blockIdx.x;               // 0..1023
  const int qt = 31 - (wid >> 5);           // descending work
  const int bh = wid & 31;
  const int bb = bh >> 4, h = bh & 15;
  const int tid = threadIdx.x, lane = tid & 63, w = tid >> 6;
  const int hi = lane >> 4, lo = lane & 15;
  __shared__ __align__(16) u16 Klds[KVB * 128];       // [kv][d]  swizzled
  __shared__ __align__(16) u16 Vlds[128 * KVB];       // [d][kv]  swizzled
  __shared__ __align__(16) unsigned P32[4][16 * 32];  // per-wave packed P
  const size_t baseQ = ((size_t)bb * SEQ_) * DM + (size_t)h * 128;
  const size_t baseV = (size_t)h * 128 * NR + (size_t)bb * SEQ_;
  const int q0 = qt * 64 + w * 16;
  bf16x8 qf[4];
  #pragma unroll
  for (int kq = 0; kq < 4; ++kq)
    qf[kq] = *(const bf16x8*)(Qp + baseQ + (size_t)(q0 + lo) * DM + kq * 32 + hi * 8);
  f32x4 o[8] = {};
  float mrow[4], lrow[4];
  #pragma unroll
  for (int r = 0; r < 4; ++r) { mrow[r] = -1e30f; lrow[r] = 0.0f; }
  unsigned* pw = &P32[w][0];
  const int ntile = qt + 1;
  for (int t = 0; t < ntile; ++t) {
    const int kb = t * KVB;
    __syncthreads();
    #pragma unroll
    for (int c = 0; c < 4; ++c) {
      const int el = ((w * 4 + c) * 64 + lane) * 8;
      const int row = el >> 7, col = el & 127;
      const int scol = col ^ ((row & 7) << 3);
      GLL(Kp + baseQ + (size_t)(kb + row) * DM + scol, Klds + el);
    }
    #pragma unroll
    for (int c = 0; c < 4; ++c) {
      const int el = ((w * 4 + c) * 64 + lane) * 8;
      const int row = el >> 6, col = el & 63;
      const int scol = col ^ ((row & 7) << 3);
      GLL(Vtp + baseV + (size_t)row * NR + kb + scol, Vlds + el);
    }
    __syncthreads();
    f32x4 sc[4] = {};
    #pragma unroll
    for (int kt = 0; kt < 4; ++kt) {
      const int krow = kt * 16 + lo;
      #pragma unroll
      for (int kq = 0; kq < 4; ++kq) {
        const int coff = (kq * 32 + hi * 8) ^ ((krow & 7) << 3);
        bf16x8 kf = *(const bf16x8*)(Klds + krow * 128 + coff);
        sc[kt] = __builtin_amdgcn_mfma_f32_16x16x32_bf16(qf[kq], kf, sc[kt], 0, 0, 0);
      }
    }
    float mt[4];
    #pragma unroll
    for (int r = 0; r < 4; ++r) mt[r] = -1e30f;
    #pragma unroll
    for (int kt = 0; kt < 4; ++kt) {
      const int kg = kb + kt * 16 + lo;
      #pragma unroll
      for (int r = 0; r < 4; ++r) {
        const int qg = q0 + hi * 4 + r;
        float sv = sc[kt][r];
        sv = (kg <= qg) ? sv : -1e30f;
        sc[kt][r] = sv;
        mt[r] = fmaxf(mt[r], sv);
      }
    }
    #pragma unroll
    for (int r = 0; r < 4; ++r) {
      #pragma unroll
      for (int off = 1; off < 16; off <<= 1) mt[r] = fmaxf(mt[r], __shfl_xor(mt[r], off));
    }
    float scl[4], lt[4];
    #pragma unroll
    for (int r = 0; r < 4; ++r) {
      const float mn = fmaxf(mrow[r], mt[r]);
      scl[r] = __expf(mrow[r] - mn);
      mrow[r] = mn;
      lt[r] = 0.0f;
    }
    float pv_[4][4];
    #pragma unroll
    for (int kt = 0; kt < 4; ++kt)
      #pragma unroll
      for (int r = 0; r < 4; ++r) {
        const float p = __expf(sc[kt][r] - mrow[r]);
        pv_[kt][r] = p;
        lt[r] += p;
      }
    #pragma unroll
    for (int r = 0; r < 4; ++r) {
      #pragma unroll
      for (int off = 1; off < 16; off <<= 1) lt[r] += __shfl_xor(lt[r], off);
      lrow[r] = lrow[r] * scl[r] + lt[r];
    }
    #pragma unroll
    for (int nt = 0; nt < 8; ++nt)
      #pragma unroll
      for (int r = 0; r < 4; ++r) o[nt][r] *= scl[r];
    #pragma unroll
    for (int kt = 0; kt < 4; ++kt)
      #pragma unroll
      for (int r = 0; r < 4; ++r) {
        const float own = pv_[kt][r];
        const float pp = __shfl_xor(own, 1);
        const unsigned lo16 = (lane & 1) ? f2bf(pp) : f2bf(own);
        const unsigned hi16 = (lane & 1) ? f2bf(own) : f2bf(pp);
        const unsigned pk = lo16 | (hi16 << 16);
        if ((lane & 1) == (kt >> 1)) {
          const int row = hi * 4 + r;
          const int kp = kt * 8 + (lo >> 1);
          const int kps = (((kp >> 2) ^ (row & 7)) << 2) | (kp & 3);
          pw[row * 32 + kps] = pk;
        }
      }
    #pragma unroll
    for (int half = 0; half < 2; ++half) {
      const int ch = (half * 4 + hi) ^ (lo & 7);
      bf16x8 pf = *(const bf16x8*)((const u16*)(pw + lo * 32 + ch * 4));
      #pragma unroll
      for (int nt = 0; nt < 8; ++nt) {
        const int vrow = nt * 16 + lo;
        const int coff = (half * 32 + hi * 8) ^ ((vrow & 7) << 3);
        bf16x8 vf = *(const bf16x8*)(Vlds + vrow * 64 + coff);
        o[nt] = __builtin_amdgcn_mfma_f32_16x16x32_bf16(pf, vf, o[nt], 0, 0, 0);
      }
    }
  }
  float inv[4];
  #pragma unroll
  for (int r = 0; r < 4; ++r) inv[r] = 1.0f / lrow[r];
  #pragma unroll
  for (int nt = 0; nt < 8; ++nt)
    #pragma unroll
    for (int r = 0; r < 4; ++r) {
      const size_t row = q0 + hi * 4 + r;
      Op[baseQ + row * DM + nt * 16 + lo] = f2bf(o[nt][r] * inv[r]);
    }
}

// ---------------- launch ----------------------------------------------------
extern "C" void kernel_launch(void* const* d_in, const int* in_sizes, int n_in,
                              void* d_out, int out_size, void* d_ws, size_t ws_size,
                              hipStream_t stream) {
  (void)in_sizes; (void)n_in; (void)out_size; (void)ws_size;
  const float* X    = (const float*)d_in[0];
  const float* Wq   = (const float*)d_in[1];
  const float* bq   = (const float*)d_in[2];
  const float* Wk   = (const float*)d_in[3];
  const float* bk   = (const float*)d_in[4];
  const float* Wv   = (const float*)d_in[5];
  const float* bv   = (const float*)d_in[6];
  const float* Wo   = (const float*)d_in[7];
  const float* bo   = (const float*)d_in[8];
  const float* Win  = (const float*)d_in[9];
  const float* bin  = (const float*)d_in[10];
  const float* Wout = (const float*)d_in[11];
  const float* bout = (const float*)d_in[12];
  const float* ln1w = (const float*)d_in[13];
  const float* ln1b = (const float*)d_in[14];
  const float* ln2w = (const float*)d_in[15];
  const float* ln2b = (const float*)d_in[16];
  float* out = (float*)d_out;

  char* ws = (char*)d_ws;
  u16* wbuf  = (u16*)ws;                      // 33,554,432 B
  u16* lnb   = (u16*)(ws + 33554432);         // 16 MB
  u16* Qb    = (u16*)(ws + 50331648);
  u16* Kb    = (u16*)(ws + 67108864);
  u16* Vtb   = (u16*)(ws + 83886080);         // V transposed [d_model][b*s]
  u16* Ob    = (u16*)(ws + 100663296);
  float* bqkv = (float*)(ws + 117440512);     // 24 KB concat bias
  u16* H1    = Qb;                            // aliases Q/K (dead by MLP)

  const int LDS256 = 2 * (256 * 64 + 256 * 64) * 2;  // 128 KiB
  const int LDS128 = 2 * (256 * 64 + 128 * 64) * 2;  // 96 KiB
  hipFuncSetAttribute((const void*)&gemm8p<4, 256>, hipFuncAttributeMaxDynamicSharedMemorySize, LDS256);
  hipFuncSetAttribute((const void*)&gemm8p<1, 256>, hipFuncAttributeMaxDynamicSharedMemorySize, LDS256);
  hipFuncSetAttribute((const void*)&gemm8p<2, 128>, hipFuncAttributeMaxDynamicSharedMemorySize, LDS128);

  // LN1
  ln_k<<<NR, 256, 0, stream>>>(X, ln1w, ln1b, lnb);
  // weights -> bf16 (Wq|Wk|Wv concat), bias concat
  cvt_bf16_k<<<2048, 256, 0, stream>>>(Wq, wbuf, DM * DM / 4);
  cvt_bf16_k<<<2048, 256, 0, stream>>>(Wk, wbuf + DM * DM, DM * DM / 4);
  cvt_bf16_k<<<2048, 256, 0, stream>>>(Wv, wbuf + 2 * DM * DM, DM * DM / 4);
  concat3_k<<<8, 256, 0, stream>>>(bq, bk, bv, bqkv);
  // fused QKV GEMM: N=6144, grid 24x16=384
  gemm8p<4, 256><<<384, 512, LDS256, stream>>>(lnb, wbuf, bqkv, nullptr,
                                               Qb, Kb, Vtb, 3 * DM, DM, 24);
  // attention
  attn_k<<<1024, 256, 0, stream>>>(Qb, Kb, Vtb, Ob);
  // X1 = X + attn_out @ Wo^T + bo -> d_out (fp32); grid 16x16=256
  cvt_bf16_k<<<2048, 256, 0, stream>>>(Wo, wbuf, DM * DM / 4);
  gemm8p<2, 128><<<256, 512, LDS128, stream>>>(Ob, wbuf, bo, X,
                                               out, nullptr, nullptr, DM, DM, 16);
  // LN2
  ln_k<<<NR, 256, 0, stream>>>(out, ln2w, ln2b, lnb);
  // H1 = gelu(ln2 @ Win^T + bin); N=8192, grid 32x16=512
  cvt_bf16_k<<<2048, 256, 0, stream>>>(Win, wbuf, DFF_ * DM / 4);
  gemm8p<1, 256><<<512, 512, LDS256, stream>>>(lnb, wbuf, bin, nullptr,
                                               H1, nullptr, nullptr, DFF_, DM, 32);
  // out = X1 + H1 @ Wout^T + bout; K=8192, grid 16x16=256
  cvt_bf16_k<<<2048, 256, 0, stream>>>(Wout, wbuf, DM * DFF_ / 4);
  gemm8p<2, 128><<<256, 512, LDS128, stream>>>(H1, wbuf, bout, out,
                                               out, nullptr, nullptr, DM, DFF_, 16);
}

// Round 4
// 643.793 us; speedup vs baseline: 1.5117x; 1.0220x over previous
//
#include <hip/hip_runtime.h>
#include <cstdint>
#include <cstddef>

#define DM 2048
#define DFF_ 8192
#define NR 4096        // B*S rows
#define SEQ_ 2048
#define KVB 64
#define QK_SCALE 0.2973017787506803f

typedef unsigned short u16;
typedef __attribute__((ext_vector_type(8))) __bf16 bf16x8;
typedef __attribute__((ext_vector_type(8))) unsigned short us8;
typedef __attribute__((ext_vector_type(4))) unsigned short us4;
typedef __attribute__((ext_vector_type(4))) float f32x4;

static __device__ __forceinline__ u16 f2bf(float f) {
  union { float f; unsigned u; } x; x.f = f;
  unsigned r = x.u + 0x7fffu + ((x.u >> 16) & 1u);
  return (u16)(r >> 16);
}

#define GLL(srcp, dstp) __builtin_amdgcn_global_load_lds( \
    (const __attribute__((address_space(1))) void*)(srcp), \
    (__attribute__((address_space(3))) void*)(dstp), 16, 0, 0)
#define BAR() __builtin_amdgcn_s_barrier()
#define SB0() __builtin_amdgcn_sched_barrier(0)
#define LGKMN(n) do { asm volatile("s_waitcnt lgkmcnt(" #n ")" ::: "memory"); SB0(); } while (0)
#define VMCN(n)  do { asm volatile("s_waitcnt vmcnt(" #n ")" ::: "memory");  SB0(); } while (0)

// ---------------- fp32 -> bf16 conversion (vectorized, grid-stride) ----------
__global__ __launch_bounds__(256) void cvt_bf16_k(const float* __restrict__ in,
                                                  u16* __restrict__ out, int n4) {
  int i = blockIdx.x * 256 + threadIdx.x;
  int st = gridDim.x * 256;
  for (; i < n4; i += st) {
    float4 v = ((const float4*)in)[i];
    us4 o;
    o.x = f2bf(v.x); o.y = f2bf(v.y); o.z = f2bf(v.z); o.w = f2bf(v.w);
    ((us4*)out)[i] = o;
  }
}

__global__ __launch_bounds__(256) void concat3_k(const float* a, const float* b,
                                                 const float* c, float* o) {
  int i = blockIdx.x * 256 + threadIdx.x;
  if (i < DM) { o[i] = a[i]; o[DM + i] = b[i]; o[2 * DM + i] = c[i]; }
}

// ---------------- LayerNorm: fp32 in -> bf16 out, one block per row ----------
__global__ __launch_bounds__(256) void ln_k(const float* __restrict__ X,
                                            const float* __restrict__ g,
                                            const float* __restrict__ be,
                                            u16* __restrict__ out) {
  const int row = blockIdx.x, tid = threadIdx.x;
  const float* x = X + (size_t)row * DM;
  float4 a0 = ((const float4*)x)[tid];
  float4 a1 = ((const float4*)x)[tid + 256];
  float s = a0.x + a0.y + a0.z + a0.w + a1.x + a1.y + a1.z + a1.w;
  float q = a0.x*a0.x + a0.y*a0.y + a0.z*a0.z + a0.w*a0.w
          + a1.x*a1.x + a1.y*a1.y + a1.z*a1.z + a1.w*a1.w;
  #pragma unroll
  for (int off = 32; off; off >>= 1) { s += __shfl_xor(s, off); q += __shfl_xor(q, off); }
  __shared__ float red[8];
  const int w = tid >> 6, lane = tid & 63;
  if (lane == 0) { red[w] = s; red[4 + w] = q; }
  __syncthreads();
  s = red[0] + red[1] + red[2] + red[3];
  q = red[4] + red[5] + red[6] + red[7];
  const float mean = s * (1.0f / DM);
  const float rstd = rsqrtf(q * (1.0f / DM) - mean * mean + 1e-5f);
  float4 g0 = ((const float4*)g)[tid], g1 = ((const float4*)g)[tid + 256];
  float4 b0 = ((const float4*)be)[tid], b1 = ((const float4*)be)[tid + 256];
  us4 o0, o1;
  o0.x = f2bf((a0.x - mean) * rstd * g0.x + b0.x);
  o0.y = f2bf((a0.y - mean) * rstd * g0.y + b0.y);
  o0.z = f2bf((a0.z - mean) * rstd * g0.z + b0.z);
  o0.w = f2bf((a0.w - mean) * rstd * g0.w + b0.w);
  o1.x = f2bf((a1.x - mean) * rstd * g1.x + b1.x);
  o1.y = f2bf((a1.y - mean) * rstd * g1.y + b1.y);
  o1.z = f2bf((a1.z - mean) * rstd * g1.z + b1.z);
  o1.w = f2bf((a1.w - mean) * rstd * g1.w + b1.w);
  us4* op = (us4*)(out + (size_t)row * DM);
  op[tid] = o0;
  op[tid + 256] = o1;
}

// ---------------- GEMM: BM=256, BN=128, BK=64, 8 waves (4M x 2N) ------------
// One barrier per K-tile. 3 LDS buffers (147KB): stage tile t+2 during tile t,
// vmcnt(6) before tile-end barrier (counted, never drain in steady state).
// Per tile: 16 ds_read_b128 in two groups; two 16-MFMA clusters with
// lgkmcnt(4)/lgkmcnt(0) so group-2 reads + staging overlap cluster-1 MFMA.
// MODE 1: bf16 gelu(acc+b)   MODE 2: f32 res+acc+b
// MODE 4: QKV fused (Q,K scaled row-major; V^T us4-packed)
template<int MODE>
__global__ __launch_bounds__(512, 1) void gemmk(
    const u16* __restrict__ A, const u16* __restrict__ W,
    const float* __restrict__ bias, const float* __restrict__ res,
    void* __restrict__ o0, void* __restrict__ o1, void* __restrict__ o2,
    int N, int K, int NX) {
  constexpr int ASZ = 256 * 64;
  constexpr int BSZ = 128 * 64;
  constexpr int TSZ = ASZ + BSZ;
  extern __shared__ __align__(16) u16 lds[];
  const int tid = threadIdx.x, lane = tid & 63, w = tid >> 6;
  const int hi = lane >> 4, lo = lane & 15;
  const int bid = blockIdx.x;
  const int swz = (bid & 7) * ((int)gridDim.x >> 3) + (bid >> 3);
  const size_t brow = (size_t)(swz / NX) * 256;
  const size_t bcol = (size_t)(swz % NX) * 128;
  const int wr = (w & 3) * 64, wc = (w >> 2) * 64;
  const int rA = tid >> 3;
  const int cA = (tid & 7) * 8;
  const int scol = cA ^ ((rA & 7) << 3);
  const int NT = K >> 6;

#define STAGE(tt, bi) do { \
    u16* tb_ = lds + (bi) * TSZ; \
    const size_t k0_ = (size_t)(tt) * 64; \
    _Pragma("unroll") \
    for (int g_ = 0; g_ < 4; ++g_) { \
      const int row_ = g_ * 64 + rA; \
      GLL(A + (brow + row_) * (size_t)K + k0_ + scol, tb_ + row_ * 64 + cA); \
    } \
    _Pragma("unroll") \
    for (int g_ = 0; g_ < 2; ++g_) { \
      const int row_ = g_ * 64 + rA; \
      GLL(W + (bcol + row_) * (size_t)K + k0_ + scol, tb_ + ASZ + row_ * 64 + cA); \
    } } while (0)

  const int koff[2] = { (hi * 8) ^ ((lo & 7) << 3), (32 + hi * 8) ^ ((lo & 7) << 3) };
  f32x4 acc[4][4] = {};

  STAGE(0, 0); STAGE(1, 1);
  VMCN(6);
  BAR();

  int cb = 0;
  for (int t = 0; t < NT; ++t) {
    const u16* Ab = lds + cb * TSZ;
    const u16* Bb = Ab + ASZ;
    bf16x8 af[4][2], b0f[2][2], b1f[2][2];
    // group 1: A frags (8) + B low-half frags (4)
    #pragma unroll
    for (int m = 0; m < 4; ++m)
      #pragma unroll
      for (int ks = 0; ks < 2; ++ks)
        af[m][ks] = *(const bf16x8*)(Ab + (wr + m * 16 + lo) * 64 + koff[ks]);
    #pragma unroll
    for (int n = 0; n < 2; ++n)
      #pragma unroll
      for (int ks = 0; ks < 2; ++ks)
        b0f[n][ks] = *(const bf16x8*)(Bb + (wc + n * 16 + lo) * 64 + koff[ks]);
    SB0();
    // stage tile t+2 (6 global_load_lds, vmcnt only)
    if (t + 2 < NT) {
      int b2 = cb + 2; if (b2 >= 3) b2 -= 3;
      STAGE(t + 2, b2);
    }
    SB0();
    // group 2: B high-half frags (4)
    #pragma unroll
    for (int n = 0; n < 2; ++n)
      #pragma unroll
      for (int ks = 0; ks < 2; ++ks)
        b1f[n][ks] = *(const bf16x8*)(Bb + (wc + 32 + n * 16 + lo) * 64 + koff[ks]);
    SB0();
    LGKMN(4);           // group 1 (12 reads) landed; group 2 may be in flight
    __builtin_amdgcn_s_setprio(1);
    #pragma unroll
    for (int m = 0; m < 4; ++m)
      #pragma unroll
      for (int n = 0; n < 2; ++n)
        #pragma unroll
        for (int ks = 0; ks < 2; ++ks)
          acc[m][n] = __builtin_amdgcn_mfma_f32_16x16x32_bf16(af[m][ks], b0f[n][ks], acc[m][n], 0, 0, 0);
    __builtin_amdgcn_s_setprio(0);
    LGKMN(0);           // group 2 landed
    __builtin_amdgcn_s_setprio(1);
    #pragma unroll
    for (int m = 0; m < 4; ++m)
      #pragma unroll
      for (int n = 0; n < 2; ++n)
        #pragma unroll
        for (int ks = 0; ks < 2; ++ks)
          acc[m][2 + n] = __builtin_amdgcn_mfma_f32_16x16x32_bf16(af[m][ks], b1f[n][ks], acc[m][2 + n], 0, 0, 0);
    __builtin_amdgcn_s_setprio(0);
    if (t + 2 < NT) { VMCN(6); }      // tile t+1 fully landed; t+2 in flight
    else if (t + 1 < NT) { VMCN(0); } // tail drain
    BAR();
    ++cb; if (cb == 3) cb = 0;
  }
#undef STAGE
  // ---- epilogue
  #pragma unroll
  for (int m = 0; m < 4; ++m) {
    #pragma unroll
    for (int n = 0; n < 4; ++n) {
      const size_t col = bcol + wc + n * 16 + lo;
      const float bv = bias[col];
      const size_t rowb = brow + wr + m * 16 + hi * 4;
      if (MODE == 4) {
        const int which = (int)(col >> 11);
        const size_t c2 = col & 2047;
        if (which == 2) {
          us4 ov;
          #pragma unroll
          for (int r = 0; r < 4; ++r) ov[r] = f2bf(acc[m][n][r] + bv);
          *(us4*)((u16*)o2 + c2 * (size_t)NR + rowb) = ov;
        } else {
          u16* dst = (u16*)(which ? o1 : o0);
          #pragma unroll
          for (int r = 0; r < 4; ++r)
            dst[(rowb + r) * (size_t)DM + c2] = f2bf((acc[m][n][r] + bv) * QK_SCALE);
        }
      } else if (MODE == 1) {
        u16* dst = (u16*)o0;
        #pragma unroll
        for (int r = 0; r < 4; ++r) {
          float v = acc[m][n][r] + bv;
          float tt = 0.7978845608028654f * (v + 0.044715f * v * v * v);
          float e2 = __expf(2.0f * tt);
          float th = 1.0f - 2.0f / (e2 + 1.0f);
          dst[(rowb + r) * (size_t)N + col] = f2bf(0.5f * v * (1.0f + th));
        }
      } else {
        float* po = (float*)o0;
        #pragma unroll
        for (int r = 0; r < 4; ++r) {
          const size_t idx = (rowb + r) * (size_t)N + col;
          po[idx] = res[idx] + acc[m][n][r] + bv;
        }
      }
    }
  }
}

// ---------------- Flash attention (causal), bf16 ----------------------------
__global__ __launch_bounds__(256) void attn_k(const u16* __restrict__ Qp,
                                              const u16* __restrict__ Kp,
                                              const u16* __restrict__ Vtp,
                                              u16* __restrict__ Op) {
  const int wid = blockIdx.x;               // 0..1023
  const int qt = 31 - (wid >> 5);           // descending work
  const int bh = wid & 31;
  const int bb = bh >> 4, h = bh & 15;
  const int tid = threadIdx.x, lane = tid & 63, w = tid >> 6;
  const int hi = lane >> 4, lo = lane & 15;
  __shared__ __align__(16) u16 Klds[KVB * 128];       // [kv][d]  swizzled
  __shared__ __align__(16) u16 Vlds[128 * KVB];       // [d][kv]  swizzled
  __shared__ __align__(16) unsigned P32[4][16 * 32];  // per-wave packed P
  const size_t baseQ = ((size_t)bb * SEQ_) * DM + (size_t)h * 128;
  const size_t baseV = (size_t)h * 128 * NR + (size_t)bb * SEQ_;
  const int q0 = qt * 64 + w * 16;
  bf16x8 qf[4];
  #pragma unroll
  for (int kq = 0; kq < 4; ++kq)
    qf[kq] = *(const bf16x8*)(Qp + baseQ + (size_t)(q0 + lo) * DM + kq * 32 + hi * 8);
  f32x4 o[8] = {};
  float mrow[4], lrow[4];
  #pragma unroll
  for (int r = 0; r < 4; ++r) { mrow[r] = -1e30f; lrow[r] = 0.0f; }
  unsigned* pw = &P32[w][0];
  const int ntile = qt + 1;
  for (int t = 0; t < ntile; ++t) {
    const int kb = t * KVB;
    __syncthreads();
    #pragma unroll
    for (int c = 0; c < 4; ++c) {
      const int el = ((w * 4 + c) * 64 + lane) * 8;
      const int row = el >> 7, col = el & 127;
      const int scol = col ^ ((row & 7) << 3);
      GLL(Kp + baseQ + (size_t)(kb + row) * DM + scol, Klds + el);
    }
    #pragma unroll
    for (int c = 0; c < 4; ++c) {
      const int el = ((w * 4 + c) * 64 + lane) * 8;
      const int row = el >> 6, col = el & 63;
      const int scol = col ^ ((row & 7) << 3);
      GLL(Vtp + baseV + (size_t)row * NR + kb + scol, Vlds + el);
    }
    __syncthreads();
    f32x4 sc[4] = {};
    #pragma unroll
    for (int kt = 0; kt < 4; ++kt) {
      const int krow = kt * 16 + lo;
      #pragma unroll
      for (int kq = 0; kq < 4; ++kq) {
        const int coff = (kq * 32 + hi * 8) ^ ((krow & 7) << 3);
        bf16x8 kf = *(const bf16x8*)(Klds + krow * 128 + coff);
        sc[kt] = __builtin_amdgcn_mfma_f32_16x16x32_bf16(qf[kq], kf, sc[kt], 0, 0, 0);
      }
    }
    float mt[4];
    #pragma unroll
    for (int r = 0; r < 4; ++r) mt[r] = -1e30f;
    #pragma unroll
    for (int kt = 0; kt < 4; ++kt) {
      const int kg = kb + kt * 16 + lo;
      #pragma unroll
      for (int r = 0; r < 4; ++r) {
        const int qg = q0 + hi * 4 + r;
        float sv = sc[kt][r];
        sv = (kg <= qg) ? sv : -1e30f;
        sc[kt][r] = sv;
        mt[r] = fmaxf(mt[r], sv);
      }
    }
    #pragma unroll
    for (int r = 0; r < 4; ++r) {
      #pragma unroll
      for (int off = 1; off < 16; off <<= 1) mt[r] = fmaxf(mt[r], __shfl_xor(mt[r], off));
    }
    float scl[4], lt[4];
    #pragma unroll
    for (int r = 0; r < 4; ++r) {
      const float mn = fmaxf(mrow[r], mt[r]);
      scl[r] = __expf(mrow[r] - mn);
      mrow[r] = mn;
      lt[r] = 0.0f;
    }
    float pv_[4][4];
    #pragma unroll
    for (int kt = 0; kt < 4; ++kt)
      #pragma unroll
      for (int r = 0; r < 4; ++r) {
        const float p = __expf(sc[kt][r] - mrow[r]);
        pv_[kt][r] = p;
        lt[r] += p;
      }
    #pragma unroll
    for (int r = 0; r < 4; ++r) {
      #pragma unroll
      for (int off = 1; off < 16; off <<= 1) lt[r] += __shfl_xor(lt[r], off);
      lrow[r] = lrow[r] * scl[r] + lt[r];
    }
    #pragma unroll
    for (int nt = 0; nt < 8; ++nt)
      #pragma unroll
      for (int r = 0; r < 4; ++r) o[nt][r] *= scl[r];
    #pragma unroll
    for (int kt = 0; kt < 4; ++kt)
      #pragma unroll
      for (int r = 0; r < 4; ++r) {
        const float own = pv_[kt][r];
        const float pp = __shfl_xor(own, 1);
        const unsigned lo16 = (lane & 1) ? f2bf(pp) : f2bf(own);
        const unsigned hi16 = (lane & 1) ? f2bf(own) : f2bf(pp);
        const unsigned pk = lo16 | (hi16 << 16);
        if ((lane & 1) == (kt >> 1)) {
          const int row = hi * 4 + r;
          const int kp = kt * 8 + (lo >> 1);
          const int kps = (((kp >> 2) ^ (row & 7)) << 2) | (kp & 3);
          pw[row * 32 + kps] = pk;
        }
      }
    #pragma unroll
    for (int half = 0; half < 2; ++half) {
      const int ch = (half * 4 + hi) ^ (lo & 7);
      bf16x8 pf = *(const bf16x8*)((const u16*)(pw + lo * 32 + ch * 4));
      #pragma unroll
      for (int nt = 0; nt < 8; ++nt) {
        const int vrow = nt * 16 + lo;
        const int coff = (half * 32 + hi * 8) ^ ((vrow & 7) << 3);
        bf16x8 vf = *(const bf16x8*)(Vlds + vrow * 64 + coff);
        o[nt] = __builtin_amdgcn_mfma_f32_16x16x32_bf16(pf, vf, o[nt], 0, 0, 0);
      }
    }
  }
  float inv[4];
  #pragma unroll
  for (int r = 0; r < 4; ++r) inv[r] = 1.0f / lrow[r];
  #pragma unroll
  for (int nt = 0; nt < 8; ++nt)
    #pragma unroll
    for (int r = 0; r < 4; ++r) {
      const size_t row = q0 + hi * 4 + r;
      Op[baseQ + row * DM + nt * 16 + lo] = f2bf(o[nt][r] * inv[r]);
    }
}

// ---------------- launch ----------------------------------------------------
extern "C" void kernel_launch(void* const* d_in, const int* in_sizes, int n_in,
                              void* d_out, int out_size, void* d_ws, size_t ws_size,
                              hipStream_t stream) {
  (void)in_sizes; (void)n_in; (void)out_size; (void)ws_size;
  const float* X    = (const float*)d_in[0];
  const float* Wq   = (const float*)d_in[1];
  const float* bq   = (const float*)d_in[2];
  const float* Wk   = (const float*)d_in[3];
  const float* bk   = (const float*)d_in[4];
  const float* Wv   = (const float*)d_in[5];
  const float* bv   = (const float*)d_in[6];
  const float* Wo   = (const float*)d_in[7];
  const float* bo   = (const float*)d_in[8];
  const float* Win  = (const float*)d_in[9];
  const float* bin  = (const float*)d_in[10];
  const float* Wout = (const float*)d_in[11];
  const float* bout = (const float*)d_in[12];
  const float* ln1w = (const float*)d_in[13];
  const float* ln1b = (const float*)d_in[14];
  const float* ln2w = (const float*)d_in[15];
  const float* ln2b = (const float*)d_in[16];
  float* out = (float*)d_out;

  char* ws = (char*)d_ws;
  u16* wbuf  = (u16*)ws;                      // 33,554,432 B
  u16* lnb   = (u16*)(ws + 33554432);         // 16 MB
  u16* Qb    = (u16*)(ws + 50331648);
  u16* Kb    = (u16*)(ws + 67108864);
  u16* Vtb   = (u16*)(ws + 83886080);         // V transposed [d_model][b*s]
  u16* Ob    = (u16*)(ws + 100663296);
  float* bqkv = (float*)(ws + 117440512);     // 24 KB concat bias
  u16* H1    = Qb;                            // aliases Q/K (dead by MLP)

  const int LDSG = 3 * (256 * 64 + 128 * 64) * 2;  // 147456 B
  hipFuncSetAttribute((const void*)&gemmk<4>, hipFuncAttributeMaxDynamicSharedMemorySize, LDSG);
  hipFuncSetAttribute((const void*)&gemmk<1>, hipFuncAttributeMaxDynamicSharedMemorySize, LDSG);
  hipFuncSetAttribute((const void*)&gemmk<2>, hipFuncAttributeMaxDynamicSharedMemorySize, LDSG);

  // LN1
  ln_k<<<NR, 256, 0, stream>>>(X, ln1w, ln1b, lnb);
  // weights -> bf16 (Wq|Wk|Wv concat), bias concat
  cvt_bf16_k<<<2048, 256, 0, stream>>>(Wq, wbuf, DM * DM / 4);
  cvt_bf16_k<<<2048, 256, 0, stream>>>(Wk, wbuf + DM * DM, DM * DM / 4);
  cvt_bf16_k<<<2048, 256, 0, stream>>>(Wv, wbuf + 2 * DM * DM, DM * DM / 4);
  concat3_k<<<8, 256, 0, stream>>>(bq, bk, bv, bqkv);
  // fused QKV GEMM: N=6144, grid 16x48=768 (3 perfect rounds)
  gemmk<4><<<768, 512, LDSG, stream>>>(lnb, wbuf, bqkv, nullptr,
                                       Qb, Kb, Vtb, 3 * DM, DM, 48);
  // attention
  attn_k<<<1024, 256, 0, stream>>>(Qb, Kb, Vtb, Ob);
  // X1 = X + attn_out @ Wo^T + bo -> d_out (fp32); grid 16x16=256
  cvt_bf16_k<<<2048, 256, 0, stream>>>(Wo, wbuf, DM * DM / 4);
  gemmk<2><<<256, 512, LDSG, stream>>>(Ob, wbuf, bo, X,
                                       out, nullptr, nullptr, DM, DM, 16);
  // LN2
  ln_k<<<NR, 256, 0, stream>>>(out, ln2w, ln2b, lnb);
  // H1 = gelu(ln2 @ Win^T + bin); N=8192, grid 16x64=1024 (4 perfect rounds)
  cvt_bf16_k<<<2048, 256, 0, stream>>>(Win, wbuf, DFF_ * DM / 4);
  gemmk<1><<<1024, 512, LDSG, stream>>>(lnb, wbuf, bin, nullptr,
                                        H1, nullptr, nullptr, DFF_, DM, 64);
  // out = X1 + H1 @ Wout^T + bout; K=8192, grid 16x16=256
  cvt_bf16_k<<<2048, 256, 0, stream>>>(Wout, wbuf, DM * DFF_ / 4);
  gemmk<2><<<256, 512, LDSG, stream>>>(H1, wbuf, bout, out,
                                       out, nullptr, nullptr, DM, DFF_, 16);
}

// Round 5
// 640.263 us; speedup vs baseline: 1.5200x; 1.0055x over previous
//
#include <hip/hip_runtime.h>
#include <cstdint>
#include <cstddef>

#define DM 2048
#define DFF_ 8192
#define NR 4096        // B*S rows
#define SEQ_ 2048
#define KVB 64
#define QK_SCALE 0.2973017787506803f

typedef unsigned short u16;
typedef __attribute__((ext_vector_type(8))) __bf16 bf16x8;
typedef __attribute__((ext_vector_type(8))) unsigned short us8;
typedef __attribute__((ext_vector_type(4))) unsigned short us4;
typedef __attribute__((ext_vector_type(4))) float f32x4;

static __device__ __forceinline__ u16 f2bf(float f) {
  union { float f; unsigned u; } x; x.f = f;
  unsigned r = x.u + 0x7fffu + ((x.u >> 16) & 1u);
  return (u16)(r >> 16);
}

#define GLL(srcp, dstp) __builtin_amdgcn_global_load_lds( \
    (const __attribute__((address_space(1))) void*)(srcp), \
    (__attribute__((address_space(3))) void*)(dstp), 16, 0, 0)
#define BAR() __builtin_amdgcn_s_barrier()
#define SB0() __builtin_amdgcn_sched_barrier(0)
#define LGKMN(n) do { asm volatile("s_waitcnt lgkmcnt(" #n ")" ::: "memory"); SB0(); } while (0)
#define VMCN(n)  do { asm volatile("s_waitcnt vmcnt(" #n ")" ::: "memory");  SB0(); } while (0)

// ---------------- fp32 -> bf16 conversion (vectorized, grid-stride) ----------
__global__ __launch_bounds__(256) void cvt_bf16_k(const float* __restrict__ in,
                                                  u16* __restrict__ out, int n4) {
  int i = blockIdx.x * 256 + threadIdx.x;
  int st = gridDim.x * 256;
  for (; i < n4; i += st) {
    float4 v = ((const float4*)in)[i];
    us4 o;
    o.x = f2bf(v.x); o.y = f2bf(v.y); o.z = f2bf(v.z); o.w = f2bf(v.w);
    ((us4*)out)[i] = o;
  }
}

__global__ __launch_bounds__(256) void concat3_k(const float* a, const float* b,
                                                 const float* c, float* o) {
  int i = blockIdx.x * 256 + threadIdx.x;
  if (i < DM) { o[i] = a[i]; o[DM + i] = b[i]; o[2 * DM + i] = c[i]; }
}

// ---------------- LayerNorm: fp32 in -> bf16 out, one block per row ----------
__global__ __launch_bounds__(256) void ln_k(const float* __restrict__ X,
                                            const float* __restrict__ g,
                                            const float* __restrict__ be,
                                            u16* __restrict__ out) {
  const int row = blockIdx.x, tid = threadIdx.x;
  const float* x = X + (size_t)row * DM;
  float4 a0 = ((const float4*)x)[tid];
  float4 a1 = ((const float4*)x)[tid + 256];
  float s = a0.x + a0.y + a0.z + a0.w + a1.x + a1.y + a1.z + a1.w;
  float q = a0.x*a0.x + a0.y*a0.y + a0.z*a0.z + a0.w*a0.w
          + a1.x*a1.x + a1.y*a1.y + a1.z*a1.z + a1.w*a1.w;
  #pragma unroll
  for (int off = 32; off; off >>= 1) { s += __shfl_xor(s, off); q += __shfl_xor(q, off); }
  __shared__ float red[8];
  const int w = tid >> 6, lane = tid & 63;
  if (lane == 0) { red[w] = s; red[4 + w] = q; }
  __syncthreads();
  s = red[0] + red[1] + red[2] + red[3];
  q = red[4] + red[5] + red[6] + red[7];
  const float mean = s * (1.0f / DM);
  const float rstd = rsqrtf(q * (1.0f / DM) - mean * mean + 1e-5f);
  float4 g0 = ((const float4*)g)[tid], g1 = ((const float4*)g)[tid + 256];
  float4 b0 = ((const float4*)be)[tid], b1 = ((const float4*)be)[tid + 256];
  us4 o0, o1;
  o0.x = f2bf((a0.x - mean) * rstd * g0.x + b0.x);
  o0.y = f2bf((a0.y - mean) * rstd * g0.y + b0.y);
  o0.z = f2bf((a0.z - mean) * rstd * g0.z + b0.z);
  o0.w = f2bf((a0.w - mean) * rstd * g0.w + b0.w);
  o1.x = f2bf((a1.x - mean) * rstd * g1.x + b1.x);
  o1.y = f2bf((a1.y - mean) * rstd * g1.y + b1.y);
  o1.z = f2bf((a1.z - mean) * rstd * g1.z + b1.z);
  o1.w = f2bf((a1.w - mean) * rstd * g1.w + b1.w);
  us4* op = (us4*)(out + (size_t)row * DM);
  op[tid] = o0;
  op[tid + 256] = o1;
}

// ---------------- GEMM: BM=256, BN=128, BK=64, 8 waves (4M x 2N) ------------
// 3 LDS buffers, stage t+2 during t (vmcnt(6), never drain in steady state).
// Register double-buffered fragments: tile t+1's 16 ds_read_b128 issue right
// after the barrier and land under tile t's 32 MFMAs (ks-outer, no dep chains).
// Persistent per-lane global pointers (+128B/tile) kill per-tile addr VALU.
// MODE 1: bf16 gelu(acc+b)   MODE 2: f32 res+acc+b
// MODE 4: QKV fused (Q,K scaled row-major; V^T us4-packed)
template<int MODE>
__global__ __launch_bounds__(512, 1) void gemmk(
    const u16* __restrict__ A, const u16* __restrict__ W,
    const float* __restrict__ bias, const float* __restrict__ res,
    void* __restrict__ o0, void* __restrict__ o1, void* __restrict__ o2,
    int N, int K, int NX) {
  constexpr int ASZ = 256 * 64;
  constexpr int BSZ = 128 * 64;
  constexpr int TSZ = ASZ + BSZ;
  extern __shared__ __align__(16) u16 lds[];
  const int tid = threadIdx.x, lane = tid & 63, w = tid >> 6;
  const int hi = lane >> 4, lo = lane & 15;
  const int bid = blockIdx.x;
  const int swz = (bid & 7) * ((int)gridDim.x >> 3) + (bid >> 3);
  const size_t brow = (size_t)(swz / NX) * 256;
  const size_t bcol = (size_t)(swz % NX) * 128;
  const int wr = (w & 3) * 64, wc = (w >> 2) * 64;
  const int rA = tid >> 3;
  const int cA = (tid & 7) * 8;
  const int scol = cA ^ ((rA & 7) << 3);
  const int NT = K >> 6;
  // persistent per-lane global pointers (advance +64 elements per staged tile)
  const u16* aP = A + (brow + rA) * (size_t)K + scol;
  const u16* wP = W + (bcol + rA) * (size_t)K + scol;
  const size_t rsA = (size_t)64 * K;     // 64-row group stride
  const int dstA = rA * 64 + cA;         // linear LDS dst (elements)
  const int k0 = (hi * 8) ^ ((lo & 7) << 3);
  const int k1 = (32 + hi * 8) ^ ((lo & 7) << 3);
  f32x4 acc[4][4] = {};
  bf16x8 Xa0[4], Xa1[4], Xb0[4], Xb1[4];
  bf16x8 Ya0[4], Ya1[4], Yb0[4], Yb1[4];
  int b2i = 2;   // buffer index for next stage (t+2)
  int bn1 = 1;   // buffer index of tile t+1 (frag prefetch)

#define STAGE6(db_) do { \
    _Pragma("unroll") for (int g_ = 0; g_ < 4; ++g_) \
      GLL(aP + g_ * rsA, (db_) + dstA + g_ * 4096); \
    _Pragma("unroll") for (int g_ = 0; g_ < 2; ++g_) \
      GLL(wP + g_ * rsA, (db_) + ASZ + dstA + g_ * 4096); \
    aP += 64; wP += 64; } while (0)

#define ITER(t_, Ca0, Ca1, Cb0, Cb1, Na0, Na1, Nb0, Nb1) do { \
    if ((t_) + 2 < NT) { STAGE6(lds + b2i * TSZ); b2i = (b2i + 1 == 3) ? 0 : b2i + 1; } \
    LGKMN(0); \
    if ((t_) + 2 < NT) { VMCN(6); } else if ((t_) + 1 < NT) { VMCN(0); } \
    BAR(); SB0(); \
    if ((t_) + 1 < NT) { \
      const u16* fb_ = lds + bn1 * TSZ; \
      _Pragma("unroll") for (int m_ = 0; m_ < 4; ++m_) { \
        Na0[m_] = *(const bf16x8*)(fb_ + (wr + m_ * 16 + lo) * 64 + k0); \
        Na1[m_] = *(const bf16x8*)(fb_ + (wr + m_ * 16 + lo) * 64 + k1); } \
      _Pragma("unroll") for (int n_ = 0; n_ < 4; ++n_) { \
        Nb0[n_] = *(const bf16x8*)(fb_ + ASZ + (wc + n_ * 16 + lo) * 64 + k0); \
        Nb1[n_] = *(const bf16x8*)(fb_ + ASZ + (wc + n_ * 16 + lo) * 64 + k1); } \
      bn1 = (bn1 + 1 == 3) ? 0 : bn1 + 1; \
    } \
    __builtin_amdgcn_s_setprio(1); \
    _Pragma("unroll") for (int m_ = 0; m_ < 4; ++m_) \
      _Pragma("unroll") for (int n_ = 0; n_ < 4; ++n_) \
        acc[m_][n_] = __builtin_amdgcn_mfma_f32_16x16x32_bf16(Ca0[m_], Cb0[n_], acc[m_][n_], 0, 0, 0); \
    _Pragma("unroll") for (int m_ = 0; m_ < 4; ++m_) \
      _Pragma("unroll") for (int n_ = 0; n_ < 4; ++n_) \
        acc[m_][n_] = __builtin_amdgcn_mfma_f32_16x16x32_bf16(Ca1[m_], Cb1[n_], acc[m_][n_], 0, 0, 0); \
    __builtin_amdgcn_s_setprio(0); \
  } while (0)

  // prologue: stage tiles 0,1; read frags(0) into X
  STAGE6(lds);
  STAGE6(lds + TSZ);
  VMCN(6);
  BAR(); SB0();
  #pragma unroll
  for (int m = 0; m < 4; ++m) {
    Xa0[m] = *(const bf16x8*)(lds + (wr + m * 16 + lo) * 64 + k0);
    Xa1[m] = *(const bf16x8*)(lds + (wr + m * 16 + lo) * 64 + k1);
  }
  #pragma unroll
  for (int n = 0; n < 4; ++n) {
    Xb0[n] = *(const bf16x8*)(lds + ASZ + (wc + n * 16 + lo) * 64 + k0);
    Xb1[n] = *(const bf16x8*)(lds + ASZ + (wc + n * 16 + lo) * 64 + k1);
  }

  for (int t = 0; t < NT; t += 2) {
    ITER(t,     Xa0, Xa1, Xb0, Xb1, Ya0, Ya1, Yb0, Yb1);
    ITER(t + 1, Ya0, Ya1, Yb0, Yb1, Xa0, Xa1, Xb0, Xb1);
  }
#undef ITER
#undef STAGE6
  // ---- epilogue
  #pragma unroll
  for (int m = 0; m < 4; ++m) {
    #pragma unroll
    for (int n = 0; n < 4; ++n) {
      const size_t col = bcol + wc + n * 16 + lo;
      const float bv = bias[col];
      const size_t rowb = brow + wr + m * 16 + hi * 4;
      if (MODE == 4) {
        const int which = (int)(col >> 11);
        const size_t c2 = col & 2047;
        if (which == 2) {
          us4 ov;
          #pragma unroll
          for (int r = 0; r < 4; ++r) ov[r] = f2bf(acc[m][n][r] + bv);
          *(us4*)((u16*)o2 + c2 * (size_t)NR + rowb) = ov;
        } else {
          u16* dst = (u16*)(which ? o1 : o0);
          #pragma unroll
          for (int r = 0; r < 4; ++r)
            dst[(rowb + r) * (size_t)DM + c2] = f2bf((acc[m][n][r] + bv) * QK_SCALE);
        }
      } else if (MODE == 1) {
        u16* dst = (u16*)o0;
        #pragma unroll
        for (int r = 0; r < 4; ++r) {
          float v = acc[m][n][r] + bv;
          float tt = 0.7978845608028654f * (v + 0.044715f * v * v * v);
          float e2 = __expf(2.0f * tt);
          float th = 1.0f - 2.0f / (e2 + 1.0f);
          dst[(rowb + r) * (size_t)N + col] = f2bf(0.5f * v * (1.0f + th));
        }
      } else {
        float* po = (float*)o0;
        #pragma unroll
        for (int r = 0; r < 4; ++r) {
          const size_t idx = (rowb + r) * (size_t)N + col;
          po[idx] = res[idx] + acc[m][n][r] + bv;
        }
      }
    }
  }
}

// ---------------- Flash attention (causal), bf16 ----------------------------
__global__ __launch_bounds__(256) void attn_k(const u16* __restrict__ Qp,
                                              const u16* __restrict__ Kp,
                                              const u16* __restrict__ Vtp,
                                              u16* __restrict__ Op) {
  const int wid = blockIdx.x;               // 0..1023
  const int qt = 31 - (wid >> 5);           // descending work
  const int bh = wid & 31;
  const int bb = bh >> 4, h = bh & 15;
  const int tid = threadIdx.x, lane = tid & 63, w = tid >> 6;
  const int hi = lane >> 4, lo = lane & 15;
  __shared__ __align__(16) u16 Klds[KVB * 128];       // [kv][d]  swizzled
  __shared__ __align__(16) u16 Vlds[128 * KVB];       // [d][kv]  swizzled
  __shared__ __align__(16) unsigned P32[4][16 * 32];  // per-wave packed P
  const size_t baseQ = ((size_t)bb * SEQ_) * DM + (size_t)h * 128;
  const size_t baseV = (size_t)h * 128 * NR + (size_t)bb * SEQ_;
  const int q0 = qt * 64 + w * 16;
  bf16x8 qf[4];
  #pragma unroll
  for (int kq = 0; kq < 4; ++kq)
    qf[kq] = *(const bf16x8*)(Qp + baseQ + (size_t)(q0 + lo) * DM + kq * 32 + hi * 8);
  f32x4 o[8] = {};
  float mrow[4], lrow[4];
  #pragma unroll
  for (int r = 0; r < 4; ++r) { mrow[r] = -1e30f; lrow[r] = 0.0f; }
  unsigned* pw = &P32[w][0];
  const int ntile = qt + 1;
  for (int t = 0; t < ntile; ++t) {
    const int kb = t * KVB;
    __syncthreads();
    #pragma unroll
    for (int c = 0; c < 4; ++c) {
      const int el = ((w * 4 + c) * 64 + lane) * 8;
      const int row = el >> 7, col = el & 127;
      const int scol = col ^ ((row & 7) << 3);
      GLL(Kp + baseQ + (size_t)(kb + row) * DM + scol, Klds + el);
    }
    #pragma unroll
    for (int c = 0; c < 4; ++c) {
      const int el = ((w * 4 + c) * 64 + lane) * 8;
      const int row = el >> 6, col = el & 63;
      const int scol = col ^ ((row & 7) << 3);
      GLL(Vtp + baseV + (size_t)row * NR + kb + scol, Vlds + el);
    }
    __syncthreads();
    f32x4 sc[4] = {};
    #pragma unroll
    for (int kq = 0; kq < 4; ++kq) {       // kq outer: no acc dep chains
      #pragma unroll
      for (int kt = 0; kt < 4; ++kt) {
        const int krow = kt * 16 + lo;
        const int coff = (kq * 32 + hi * 8) ^ ((krow & 7) << 3);
        bf16x8 kf = *(const bf16x8*)(Klds + krow * 128 + coff);
        sc[kt] = __builtin_amdgcn_mfma_f32_16x16x32_bf16(qf[kq], kf, sc[kt], 0, 0, 0);
      }
    }
    float mt[4];
    #pragma unroll
    for (int r = 0; r < 4; ++r) mt[r] = -1e30f;
    #pragma unroll
    for (int kt = 0; kt < 4; ++kt) {
      const int kg = kb + kt * 16 + lo;
      #pragma unroll
      for (int r = 0; r < 4; ++r) {
        const int qg = q0 + hi * 4 + r;
        float sv = sc[kt][r];
        sv = (kg <= qg) ? sv : -1e30f;
        sc[kt][r] = sv;
        mt[r] = fmaxf(mt[r], sv);
      }
    }
    #pragma unroll
    for (int r = 0; r < 4; ++r) {
      #pragma unroll
      for (int off = 1; off < 16; off <<= 1) mt[r] = fmaxf(mt[r], __shfl_xor(mt[r], off));
    }
    float scl[4], lt[4];
    #pragma unroll
    for (int r = 0; r < 4; ++r) {
      const float mn = fmaxf(mrow[r], mt[r]);
      scl[r] = __expf(mrow[r] - mn);
      mrow[r] = mn;
      lt[r] = 0.0f;
    }
    float pv_[4][4];
    #pragma unroll
    for (int kt = 0; kt < 4; ++kt)
      #pragma unroll
      for (int r = 0; r < 4; ++r) {
        const float p = __expf(sc[kt][r] - mrow[r]);
        pv_[kt][r] = p;
        lt[r] += p;
      }
    #pragma unroll
    for (int r = 0; r < 4; ++r) {
      #pragma unroll
      for (int off = 1; off < 16; off <<= 1) lt[r] += __shfl_xor(lt[r], off);
      lrow[r] = lrow[r] * scl[r] + lt[r];
    }
    #pragma unroll
    for (int nt = 0; nt < 8; ++nt)
      #pragma unroll
      for (int r = 0; r < 4; ++r) o[nt][r] *= scl[r];
    #pragma unroll
    for (int kt = 0; kt < 4; ++kt)
      #pragma unroll
      for (int r = 0; r < 4; ++r) {
        const float own = pv_[kt][r];
        const float pp = __shfl_xor(own, 1);
        const unsigned lo16 = (lane & 1) ? f2bf(pp) : f2bf(own);
        const unsigned hi16 = (lane & 1) ? f2bf(own) : f2bf(pp);
        const unsigned pk = lo16 | (hi16 << 16);
        if ((lane & 1) == (kt >> 1)) {
          const int row = hi * 4 + r;
          const int kp = kt * 8 + (lo >> 1);
          const int kps = (((kp >> 2) ^ (row & 7)) << 2) | (kp & 3);
          pw[row * 32 + kps] = pk;
        }
      }
    #pragma unroll
    for (int half = 0; half < 2; ++half) {
      const int ch = (half * 4 + hi) ^ (lo & 7);
      bf16x8 pf = *(const bf16x8*)((const u16*)(pw + lo * 32 + ch * 4));
      #pragma unroll
      for (int nt = 0; nt < 8; ++nt) {
        const int vrow = nt * 16 + lo;
        const int coff = (half * 32 + hi * 8) ^ ((vrow & 7) << 3);
        bf16x8 vf = *(const bf16x8*)(Vlds + vrow * 64 + coff);
        o[nt] = __builtin_amdgcn_mfma_f32_16x16x32_bf16(pf, vf, o[nt], 0, 0, 0);
      }
    }
  }
  float inv[4];
  #pragma unroll
  for (int r = 0; r < 4; ++r) inv[r] = 1.0f / lrow[r];
  #pragma unroll
  for (int nt = 0; nt < 8; ++nt)
    #pragma unroll
    for (int r = 0; r < 4; ++r) {
      const size_t row = q0 + hi * 4 + r;
      Op[baseQ + row * DM + nt * 16 + lo] = f2bf(o[nt][r] * inv[r]);
    }
}

// ---------------- launch ----------------------------------------------------
extern "C" void kernel_launch(void* const* d_in, const int* in_sizes, int n_in,
                              void* d_out, int out_size, void* d_ws, size_t ws_size,
                              hipStream_t stream) {
  (void)in_sizes; (void)n_in; (void)out_size; (void)ws_size;
  const float* X    = (const float*)d_in[0];
  const float* Wq   = (const float*)d_in[1];
  const float* bq   = (const float*)d_in[2];
  const float* Wk   = (const float*)d_in[3];
  const float* bk   = (const float*)d_in[4];
  const float* Wv   = (const float*)d_in[5];
  const float* bv   = (const float*)d_in[6];
  const float* Wo   = (const float*)d_in[7];
  const float* bo   = (const float*)d_in[8];
  const float* Win  = (const float*)d_in[9];
  const float* bin  = (const float*)d_in[10];
  const float* Wout = (const float*)d_in[11];
  const float* bout = (const float*)d_in[12];
  const float* ln1w = (const float*)d_in[13];
  const float* ln1b = (const float*)d_in[14];
  const float* ln2w = (const float*)d_in[15];
  const float* ln2b = (const float*)d_in[16];
  float* out = (float*)d_out;

  char* ws = (char*)d_ws;
  u16* wbuf  = (u16*)ws;                      // 33,554,432 B
  u16* lnb   = (u16*)(ws + 33554432);         // 16 MB
  u16* Qb    = (u16*)(ws + 50331648);
  u16* Kb    = (u16*)(ws + 67108864);
  u16* Vtb   = (u16*)(ws + 83886080);         // V transposed [d_model][b*s]
  u16* Ob    = (u16*)(ws + 100663296);
  float* bqkv = (float*)(ws + 117440512);     // 24 KB concat bias
  u16* H1    = Qb;                            // aliases Q/K (dead by MLP)

  const int LDSG = 3 * (256 * 64 + 128 * 64) * 2;  // 147456 B
  hipFuncSetAttribute((const void*)&gemmk<4>, hipFuncAttributeMaxDynamicSharedMemorySize, LDSG);
  hipFuncSetAttribute((const void*)&gemmk<1>, hipFuncAttributeMaxDynamicSharedMemorySize, LDSG);
  hipFuncSetAttribute((const void*)&gemmk<2>, hipFuncAttributeMaxDynamicSharedMemorySize, LDSG);

  // LN1
  ln_k<<<NR, 256, 0, stream>>>(X, ln1w, ln1b, lnb);
  // weights -> bf16 (Wq|Wk|Wv concat), bias concat
  cvt_bf16_k<<<2048, 256, 0, stream>>>(Wq, wbuf, DM * DM / 4);
  cvt_bf16_k<<<2048, 256, 0, stream>>>(Wk, wbuf + DM * DM, DM * DM / 4);
  cvt_bf16_k<<<2048, 256, 0, stream>>>(Wv, wbuf + 2 * DM * DM, DM * DM / 4);
  concat3_k<<<8, 256, 0, stream>>>(bq, bk, bv, bqkv);
  // fused QKV GEMM: N=6144, grid 16x48=768 (3 perfect rounds)
  gemmk<4><<<768, 512, LDSG, stream>>>(lnb, wbuf, bqkv, nullptr,
                                       Qb, Kb, Vtb, 3 * DM, DM, 48);
  // attention
  attn_k<<<1024, 256, 0, stream>>>(Qb, Kb, Vtb, Ob);
  // X1 = X + attn_out @ Wo^T + bo -> d_out (fp32); grid 16x16=256
  cvt_bf16_k<<<2048, 256, 0, stream>>>(Wo, wbuf, DM * DM / 4);
  gemmk<2><<<256, 512, LDSG, stream>>>(Ob, wbuf, bo, X,
                                       out, nullptr, nullptr, DM, DM, 16);
  // LN2
  ln_k<<<NR, 256, 0, stream>>>(out, ln2w, ln2b, lnb);
  // H1 = gelu(ln2 @ Win^T + bin); N=8192, grid 16x64=1024 (4 perfect rounds)
  cvt_bf16_k<<<2048, 256, 0, stream>>>(Win, wbuf, DFF_ * DM / 4);
  gemmk<1><<<1024, 512, LDSG, stream>>>(lnb, wbuf, bin, nullptr,
                                        H1, nullptr, nullptr, DFF_, DM, 64);
  // out = X1 + H1 @ Wout^T + bout; K=8192, grid 16x16=256
  cvt_bf16_k<<<2048, 256, 0, stream>>>(Wout, wbuf, DM * DFF_ / 4);
  gemmk<2><<<256, 512, LDSG, stream>>>(H1, wbuf, bout, out,
                                       out, nullptr, nullptr, DM, DFF_, 16);
}